// Round 13
// baseline (1113.467 us; speedup 1.0000x reference)
//
#include <hip/hip_runtime.h>
#include <math.h>

#define NBLK 256   // encoder blocks: 8 waves (512 thr), 1 block/CU

typedef float    f32x4 __attribute__((ext_vector_type(4)));
typedef _Float16 f16x4 __attribute__((ext_vector_type(4)));
typedef _Float16 f16x2 __attribute__((ext_vector_type(2)));

// classic MFMA spelling (pre-gfx950 builtins have no underscore before the type)
#define MFMA16(A,B,C) __builtin_amdgcn_mfma_f32_16x16x16f16((A),(B),(C),0,0,0)

// ---------- math helpers ----------
__device__ __forceinline__ float fast_rcp(float x) {
#if __has_builtin(__builtin_amdgcn_rcpf)
    return __builtin_amdgcn_rcpf(x);
#else
    return 1.0f / x;
#endif
}

// exact GELU: 0.5*x*(1+erf(x/sqrt(2))), erf via Abramowitz-Stegun 7.1.26 (|err|<1.5e-7)
__device__ __forceinline__ float gelu_exact(float x) {
    float u  = x * 0.70710678118654752440f;
    float au = fabsf(u);
    float t  = fast_rcp(fmaf(0.3275911f, au, 1.0f));
    float p  = t * fmaf(t, fmaf(t, fmaf(t, fmaf(t, 1.061405429f, -1.453152027f),
                       1.421413741f), -0.284496736f), 0.254829592f);
    float e  = __expf(-(au * au));
    float er = fmaf(-p, e, 1.0f);
    er = copysignf(er, u);
    return 0.5f * x * (1.0f + er);
}

__device__ __forceinline__ f16x2 pk_from(float a, float b) {
#if __has_builtin(__builtin_amdgcn_cvt_pkrtz)
    auto r = __builtin_amdgcn_cvt_pkrtz(a, b);   // __fp16 ext_vector(2): same bits
    f16x2 out;
    __builtin_memcpy(&out, &r, sizeof(out));
    return out;
#else
    return (f16x2){(_Float16)a, (_Float16)b};
#endif
}
__device__ __forceinline__ f16x2 pk_max(f16x2 a, f16x2 b) {
#if __has_builtin(__builtin_elementwise_max)
    return __builtin_elementwise_max(a, b);
#else
    f16x2 r; r[0] = a[0] > b[0] ? a[0] : b[0]; r[1] = a[1] > b[1] ? a[1] : b[1]; return r;
#endif
}

// ---------- fused encoder: B-operand-chained MFMA, zero activation staging ----------
// r11 residual: ~150 DS ops/wave/tile for act staging + 96 LN shuffles (MfmaUtil
// 12%, VALUBusy 58%). Fix: weights ride the A operand (row=out_ch), activations
// the B operand (col=pt, k=in_ch). MFMA D-layout (lane: rows 4*l4+r, col l15)
// IS the next layer's B-fragment layout (k=4*l4+j, col=l15) -> normalized
// activations pass layer-to-layer entirely in registers. LN stats are per-point
// scalars (2 shfl rounds over l4). L0 bias rides a K=16 bias row (k=3, act=1).
// L2: stats pass (mt0-7 discard) + pass B (kept) + recompute pass A (+64 MFMA,
// pipe idle) to stay within the 512-thr 128-VGPR cap (empirical: cap=65536/thr).
// Max-pool as packed f16 pairs (cvt_pkrtz + pk_max), 32 VGPR.
// Lane maps (r9/r11 HW-validated): A row=l%16,k=4*(l/16)+j; B col=l%16 same k;
// D col=l&15, row=4*(l>>4)+reg.
__global__ void __launch_bounds__(512, 1)
enc_kernel(const float* __restrict__ pts, int N,
           const float* __restrict__ W0, const float* __restrict__ B0,
           const float* __restrict__ G0, const float* __restrict__ E0,
           const float* __restrict__ W1, const float* __restrict__ B1,
           const float* __restrict__ G1, const float* __restrict__ E1,
           const float* __restrict__ W2, const float* __restrict__ B2,
           const float* __restrict__ G2, const float* __restrict__ E2,
           float* __restrict__ part)
{
    __shared__ __align__(16) _Float16 w1a[8*4*64*4];    // 16 KB  [mt][ks][lane][4]
    __shared__ __align__(16) _Float16 w2a[16*8*64*4];   // 64 KB  [mt][ks][lane][4]
    __shared__ __align__(16) float v0s[128];            // G0|E0
    __shared__ __align__(16) float v1s[384];            // B1|G1|E1
    __shared__ __align__(16) float v2s[768];            // B2|G2|E2

    const int tid  = threadIdx.x;
    const int lane = tid & 63;
    const int wid  = tid >> 6;     // 0..7
    const int l15  = lane & 15;
    const int l4   = lane >> 4;    // 0..3

    // ---- one-time: pack W1/W2 into A-fragment order (row=out_ch, k=in_ch) ----
    #pragma unroll
    for (int e = 0; e < 4; ++e) {   // w1a: 8mt x 4ks x 64 = 2048 entries
        int idx = tid + e*512;
        int l = idx & 63, ks = (idx >> 6) & 3, mt = idx >> 8;
        int k0 = ks*16 + ((l >> 4) << 2);
        int ch = mt*16 + (l & 15);
        f16x4 v;
        #pragma unroll
        for (int j = 0; j < 4; ++j) v[j] = (_Float16)W1[(k0 + j)*128 + ch];
        *(f16x4*)&w1a[idx*4] = v;
    }
    #pragma unroll
    for (int e = 0; e < 16; ++e) {  // w2a: 16mt x 8ks x 64 = 8192 entries
        int idx = tid + e*512;
        int l = idx & 63, ks = (idx >> 6) & 7, mt = idx >> 9;
        int k0 = ks*16 + ((l >> 4) << 2);
        int ch = mt*16 + (l & 15);
        f16x4 v;
        #pragma unroll
        for (int j = 0; j < 4; ++j) v[j] = (_Float16)W2[(k0 + j)*256 + ch];
        *(f16x4*)&w2a[idx*4] = v;
    }
    if (tid < 64)  { v0s[tid] = G0[tid]; v0s[64 + tid] = E0[tid]; }
    if (tid >= 128 && tid < 256) {
        int c = tid - 128;
        v1s[c] = B1[c]; v1s[128 + c] = G1[c]; v1s[256 + c] = E1[c];
    }
    if (tid >= 256) {
        int c = tid - 256;
        v2s[c] = B2[c]; v2s[256 + c] = G2[c]; v2s[512 + c] = E2[c];
    }

    // ---- W0 A-fragments in registers: row=out_ch mt*16+l15, k rows 0-2=W0, 3=B0 ----
    f16x4 w0a[4];
    #pragma unroll
    for (int mt = 0; mt < 4; ++mt) {
        int ch = mt*16 + l15;
        #pragma unroll
        for (int j = 0; j < 4; ++j) {
            int k = l4*4 + j;
            float w = 0.f;
            if (k < 3)       w = W0[k*64 + ch];
            else if (k == 3) w = B0[ch];
            w0a[mt][j] = (_Float16)w;
        }
    }
    __syncthreads();

    const _Float16 NI = (_Float16)(-INFINITY);
    f16x2 run[32];
    #pragma unroll
    for (int i = 0; i < 32; ++i) run[i] = (f16x2){NI, NI};

    const int tiles = (N + 127) >> 7;
    for (int t = blockIdx.x; t < tiles; t += NBLK) {
        const int p  = t*128 + wid*16 + l15;    // this lane's point
        const bool pv = (p < N);

        // ---- L0 B-frag from coords: col=pt=l15, k=4*l4+j (k0..2=xyz, k3=1 bias) ----
        f16x4 bx = {(_Float16)0, (_Float16)0, (_Float16)0, (_Float16)0};
        if (l4 == 0) {
            if (pv) {
                bx[0] = (_Float16)pts[p*3];
                bx[1] = (_Float16)pts[p*3+1];
                bx[2] = (_Float16)pts[p*3+2];
            }
            bx[3] = (_Float16)1.0f;
        }
        f32x4 acc0[4];
        #pragma unroll
        for (int mt = 0; mt < 4; ++mt) {
            acc0[mt] = (f32x4){0.f, 0.f, 0.f, 0.f};
            acc0[mt] = MFMA16(w0a[mt], bx, acc0[mt]);
        }
        // LN(64): per-point scalar stats; lane group {l4} covers all 64 ch
        f16x4 b0f[4];
        {
            float s = 0.f, q = 0.f;
            #pragma unroll
            for (int mt = 0; mt < 4; ++mt)
                #pragma unroll
                for (int r = 0; r < 4; ++r) { s += acc0[mt][r]; q = fmaf(acc0[mt][r], acc0[mt][r], q); }
            s += __shfl_xor(s, 16, 64); s += __shfl_xor(s, 32, 64);
            q += __shfl_xor(q, 16, 64); q += __shfl_xor(q, 32, 64);
            float mu = s * (1.0f/64.0f);
            float rs = rsqrtf(q * (1.0f/64.0f) - mu*mu + 1e-5f);
            #pragma unroll
            for (int mt = 0; mt < 4; ++mt) {
                f32x4 g4 = *(const f32x4*)&v0s[mt*16 + 4*l4];
                f32x4 e4 = *(const f32x4*)&v0s[64 + mt*16 + 4*l4];
                float v0 = gelu_exact(fmaf((acc0[mt][0]-mu)*rs, g4[0], e4[0]));
                float v1 = gelu_exact(fmaf((acc0[mt][1]-mu)*rs, g4[1], e4[1]));
                float v2 = gelu_exact(fmaf((acc0[mt][2]-mu)*rs, g4[2], e4[2]));
                float v3 = gelu_exact(fmaf((acc0[mt][3]-mu)*rs, g4[3], e4[3]));
                f16x2 lo = pk_from(v0, v1), hi = pk_from(v2, v3);
                b0f[mt] = (f16x4){lo[0], lo[1], hi[0], hi[1]};
            }
        }

        // ---- L1: 128 out-ch = 8 mt; K=64 = 4 ks; acts chained via B ----
        f32x4 acc1[8];
        #pragma unroll
        for (int mt = 0; mt < 8; ++mt) acc1[mt] = *(const f32x4*)&v1s[mt*16 + 4*l4];
        #pragma unroll
        for (int ks = 0; ks < 4; ++ks)
            #pragma unroll
            for (int mt = 0; mt < 8; ++mt) {
                f16x4 Aw = *(const f16x4*)&w1a[((mt*4 + ks)*64 + lane)*4];
                acc1[mt] = MFMA16(Aw, b0f[ks], acc1[mt]);
            }
        f16x4 b1f[8];
        {
            float s = 0.f, q = 0.f;
            #pragma unroll
            for (int mt = 0; mt < 8; ++mt)
                #pragma unroll
                for (int r = 0; r < 4; ++r) { s += acc1[mt][r]; q = fmaf(acc1[mt][r], acc1[mt][r], q); }
            s += __shfl_xor(s, 16, 64); s += __shfl_xor(s, 32, 64);
            q += __shfl_xor(q, 16, 64); q += __shfl_xor(q, 32, 64);
            float mu = s * (1.0f/128.0f);
            float rs = rsqrtf(q * (1.0f/128.0f) - mu*mu + 1e-5f);
            #pragma unroll
            for (int mt = 0; mt < 8; ++mt) {
                f32x4 g4 = *(const f32x4*)&v1s[128 + mt*16 + 4*l4];
                f32x4 e4 = *(const f32x4*)&v1s[256 + mt*16 + 4*l4];
                float v0 = gelu_exact(fmaf((acc1[mt][0]-mu)*rs, g4[0], e4[0]));
                float v1 = gelu_exact(fmaf((acc1[mt][1]-mu)*rs, g4[1], e4[1]));
                float v2 = gelu_exact(fmaf((acc1[mt][2]-mu)*rs, g4[2], e4[2]));
                float v3 = gelu_exact(fmaf((acc1[mt][3]-mu)*rs, g4[3], e4[3]));
                f16x2 lo = pk_from(v0, v1), hi = pk_from(v2, v3);
                b1f[mt] = (f16x4){lo[0], lo[1], hi[0], hi[1]};
            }
        }

        // ---- L2: 256 out-ch = 16 mt; K=128 = 8 ks; stats pass + recompute ----
        float sT = 0.f, qT = 0.f;
        {   // pass A (mt 0..7): stats only
            f32x4 acc2[8];
            #pragma unroll
            for (int mt = 0; mt < 8; ++mt) acc2[mt] = *(const f32x4*)&v2s[mt*16 + 4*l4];
            #pragma unroll
            for (int ks = 0; ks < 8; ++ks)
                #pragma unroll
                for (int mt = 0; mt < 8; ++mt) {
                    f16x4 Aw = *(const f16x4*)&w2a[((mt*8 + ks)*64 + lane)*4];
                    acc2[mt] = MFMA16(Aw, b1f[ks], acc2[mt]);
                }
            #pragma unroll
            for (int mt = 0; mt < 8; ++mt)
                #pragma unroll
                for (int r = 0; r < 4; ++r) { sT += acc2[mt][r]; qT = fmaf(acc2[mt][r], acc2[mt][r], qT); }
        }
        f32x4 acc2[8];   // pass B (mt 8..15): kept
        #pragma unroll
        for (int mt = 0; mt < 8; ++mt) acc2[mt] = *(const f32x4*)&v2s[(mt+8)*16 + 4*l4];
        #pragma unroll
        for (int ks = 0; ks < 8; ++ks)
            #pragma unroll
            for (int mt = 0; mt < 8; ++mt) {
                f16x4 Aw = *(const f16x4*)&w2a[(((mt+8)*8 + ks)*64 + lane)*4];
                acc2[mt] = MFMA16(Aw, b1f[ks], acc2[mt]);
            }
        #pragma unroll
        for (int mt = 0; mt < 8; ++mt)
            #pragma unroll
            for (int r = 0; r < 4; ++r) { sT += acc2[mt][r]; qT = fmaf(acc2[mt][r], acc2[mt][r], qT); }
        sT += __shfl_xor(sT, 16, 64); sT += __shfl_xor(sT, 32, 64);
        qT += __shfl_xor(qT, 16, 64); qT += __shfl_xor(qT, 32, 64);
        const float mu2 = sT * (1.0f/256.0f);
        const float rs2 = rsqrtf(qT * (1.0f/256.0f) - mu2*mu2 + 1e-5f);
        const f16x2 NIP = (f16x2){NI, NI};
        #pragma unroll
        for (int mt = 0; mt < 8; ++mt) {   // normalize+max pass B (nt = mt+8)
            f32x4 g4 = *(const f32x4*)&v2s[256 + (mt+8)*16 + 4*l4];
            f32x4 e4 = *(const f32x4*)&v2s[512 + (mt+8)*16 + 4*l4];
            float v0 = gelu_exact(fmaf((acc2[mt][0]-mu2)*rs2, g4[0], e4[0]));
            float v1 = gelu_exact(fmaf((acc2[mt][1]-mu2)*rs2, g4[1], e4[1]));
            float v2 = gelu_exact(fmaf((acc2[mt][2]-mu2)*rs2, g4[2], e4[2]));
            float v3 = gelu_exact(fmaf((acc2[mt][3]-mu2)*rs2, g4[3], e4[3]));
            f16x2 p0 = pv ? pk_from(v0, v1) : NIP;
            f16x2 p1 = pv ? pk_from(v2, v3) : NIP;
            run[(mt+8)*2]   = pk_max(run[(mt+8)*2],   p0);
            run[(mt+8)*2+1] = pk_max(run[(mt+8)*2+1], p1);
        }
        // recompute pass A (mt 0..7) and normalize+max
        #pragma unroll
        for (int mt = 0; mt < 8; ++mt) acc2[mt] = *(const f32x4*)&v2s[mt*16 + 4*l4];
        #pragma unroll
        for (int ks = 0; ks < 8; ++ks)
            #pragma unroll
            for (int mt = 0; mt < 8; ++mt) {
                f16x4 Aw = *(const f16x4*)&w2a[((mt*8 + ks)*64 + lane)*4];
                acc2[mt] = MFMA16(Aw, b1f[ks], acc2[mt]);
            }
        #pragma unroll
        for (int mt = 0; mt < 8; ++mt) {
            f32x4 g4 = *(const f32x4*)&v2s[256 + mt*16 + 4*l4];
            f32x4 e4 = *(const f32x4*)&v2s[512 + mt*16 + 4*l4];
            float v0 = gelu_exact(fmaf((acc2[mt][0]-mu2)*rs2, g4[0], e4[0]));
            float v1 = gelu_exact(fmaf((acc2[mt][1]-mu2)*rs2, g4[1], e4[1]));
            float v2 = gelu_exact(fmaf((acc2[mt][2]-mu2)*rs2, g4[2], e4[2]));
            float v3 = gelu_exact(fmaf((acc2[mt][3]-mu2)*rs2, g4[3], e4[3]));
            f16x2 p0 = pv ? pk_from(v0, v1) : NIP;
            f16x2 p1 = pv ? pk_from(v2, v3) : NIP;
            run[mt*2]   = pk_max(run[mt*2],   p0);
            run[mt*2+1] = pk_max(run[mt*2+1], p1);
        }
    }

    // ---------- epilogue: reduce over l15, merge waves via pm overlay on w1a ----------
    __syncthreads();
    float* pm = (float*)w1a;   // 8 KB region, weights dead now
    #pragma unroll
    for (int nt = 0; nt < 16; ++nt)
        #pragma unroll
        for (int pr = 0; pr < 2; ++pr) {
            float v0 = (float)run[nt*2+pr][0];
            float v1 = (float)run[nt*2+pr][1];
            #pragma unroll
            for (int m = 1; m < 16; m <<= 1) {
                v0 = fmaxf(v0, __shfl_xor(v0, m, 64));
                v1 = fmaxf(v1, __shfl_xor(v1, m, 64));
            }
            if (l15 == 0) {
                pm[wid*256 + nt*16 + 4*l4 + pr*2]     = v0;
                pm[wid*256 + nt*16 + 4*l4 + pr*2 + 1] = v1;
            }
        }
    __syncthreads();
    if (tid < 256) {
        float v = pm[tid];
        #pragma unroll
        for (int w = 1; w < 8; ++w) v = fmaxf(v, pm[w*256 + tid]);
        part[(size_t)blockIdx.x * 256 + tid] = v;
    }
}

// ---------- reduce partials -> pooled(256); z_e = pooled @ oW + ob ----------
__global__ void __launch_bounds__(256)
pool_ze_kernel(const float* __restrict__ part, const float* __restrict__ oW,
               const float* __restrict__ ob, float* __restrict__ out_ze,
               float* __restrict__ ws_ze)
{
    __shared__ float pooled[256];
    const int j = threadIdx.x;
    float m0 = -INFINITY, m1 = -INFINITY, m2 = -INFINITY, m3 = -INFINITY;
    for (int b = 0; b < NBLK; b += 4) {
        m0 = fmaxf(m0, part[(b+0)*256 + j]);
        m1 = fmaxf(m1, part[(b+1)*256 + j]);
        m2 = fmaxf(m2, part[(b+2)*256 + j]);
        m3 = fmaxf(m3, part[(b+3)*256 + j]);
    }
    pooled[j] = fmaxf(fmaxf(m0, m1), fmaxf(m2, m3));
    __syncthreads();
    float a0 = 0.f, a1 = 0.f;
    for (int k = 0; k < 256; k += 2) {
        a0 = fmaf(pooled[k],   oW[(k  )*256 + j], a0);
        a1 = fmaf(pooled[k+1], oW[(k+1)*256 + j], a1);
    }
    float z = (a0 + a1) + ob[j];
    out_ze[j] = z;
    ws_ze[j]  = z;
}

// ---------- distances over codebook + per-block argmin partials ----------
__global__ void __launch_bounds__(256)
quant_kernel(const float* __restrict__ cb, const float* __restrict__ ze,
             float* __restrict__ qpart)
{
    const int lane = threadIdx.x & 63;
    const int wid  = threadIdx.x >> 6;
    const int gw   = (int)blockIdx.x * 4 + wid;   // 256 waves total
    const float4* cb4 = (const float4*)cb;
    const float4* z4p = (const float4*)ze;
    const float4  z   = z4p[lane];

    float bv = INFINITY;
    int   bi = 0x7fffffff;
    for (int code = gw; code < 8192; code += 256) {
        float4 c = cb4[code*64 + lane];
        float d = c.x*c.x + c.y*c.y + c.z*c.z + c.w*c.w
                - 2.0f*(c.x*z.x + c.y*z.y + c.z*z.z + c.w*z.w);
        #pragma unroll
        for (int m = 1; m < 64; m <<= 1) d += __shfl_xor(d, m, 64);
        if (d < bv) { bv = d; bi = code; }   // per-wave codes ascending; strict < keeps first
    }
    __shared__ float sv[4];
    __shared__ int   si[4];
    if (lane == 0) { sv[wid] = bv; si[wid] = bi; }
    __syncthreads();
    if (threadIdx.x == 0) {
        float v = sv[0]; int i = si[0];
        for (int w = 1; w < 4; ++w)
            if (sv[w] < v || (sv[w] == v && si[w] < i)) { v = sv[w]; i = si[w]; }
        qpart[blockIdx.x*2]     = v;
        qpart[blockIdx.x*2 + 1] = __int_as_float(i);
    }
}

// ---------- decoder block body: x(KIN) @ W(KIN,512) + b -> LN(512) -> GELU ----------
template<int KIN>
__device__ __forceinline__ void dec_block_body(const float* xs, const float* __restrict__ W,
        const float* __restrict__ B, const float* __restrict__ G,
        const float* __restrict__ E, float* __restrict__ xout, float* red)
{
    const int j = threadIdx.x;  // 512 threads
    float a0=0,a1=0,a2=0,a3=0;
    for (int k = 0; k < KIN; k += 4) {
        a0 = fmaf(xs[k  ], W[(k  )*512 + j], a0);
        a1 = fmaf(xs[k+1], W[(k+1)*512 + j], a1);
        a2 = fmaf(xs[k+2], W[(k+2)*512 + j], a2);
        a3 = fmaf(xs[k+3], W[(k+3)*512 + j], a3);
    }
    float acc = ((a0+a1)+(a2+a3)) + B[j];
    float s = acc, q = acc*acc;
    #pragma unroll
    for (int m = 1; m < 64; m <<= 1) { s += __shfl_xor(s, m, 64); q += __shfl_xor(q, m, 64); }
    const int wid = j >> 6, lane = j & 63;
    if (lane == 0) { red[wid*2] = s; red[wid*2+1] = q; }
    __syncthreads();
    float ts = 0.f, tq = 0.f;
    #pragma unroll
    for (int w = 0; w < 8; ++w) { ts += red[w*2]; tq += red[w*2+1]; }
    float mu  = ts * (1.0f/512.0f);
    float var = tq * (1.0f/512.0f) - mu*mu;
    float v = fmaf((acc - mu) * rsqrtf(var + 1e-5f), G[j], E[j]);
    xout[j] = gelu_exact(v);
}

// ---------- final argmin + z_q + straight-through + decoder layer 0 ----------
__global__ void __launch_bounds__(512)
argmin_d0_kernel(const float* __restrict__ qpart, const float* __restrict__ cb,
                 const float* __restrict__ ze,
                 const float* __restrict__ W, const float* __restrict__ B,
                 const float* __restrict__ G, const float* __restrict__ E,
                 float* __restrict__ out_zq, float* __restrict__ xout)
{
    __shared__ float xs[256];
    __shared__ float red[16];
    __shared__ int   sidx;
    const int j = threadIdx.x;
    if (j == 0) {
        float bv = INFINITY; int bi = 0x7fffffff;
        for (int b = 0; b < 64; ++b) {
            float v = qpart[b*2];
            int   i = __float_as_int(qpart[b*2 + 1]);
            if (v < bv || (v == bv && i < bi)) { bv = v; bi = i; }
        }
        sidx = bi;
    }
    __syncthreads();
    const int idx = sidx;
    if (j < 256) {
        float zq = cb[(size_t)idx*256 + j];
        out_zq[j] = zq;
        float z = ze[j];
        xs[j] = z + (zq - z);   // straight-through forward, matching ref fp ops
    }
    __syncthreads();
    dec_block_body<256>(xs, W, B, G, E, xout, red);
}

__global__ void __launch_bounds__(512)
dec_layer_kernel(const float* __restrict__ xin, const float* __restrict__ W,
                 const float* __restrict__ B, const float* __restrict__ G,
                 const float* __restrict__ E, float* __restrict__ xout)
{
    __shared__ float xs[512];
    __shared__ float red[16];
    xs[threadIdx.x] = xin[threadIdx.x];
    __syncthreads();
    dec_block_body<512>(xs, W, B, G, E, xout, red);
}

// ---------- final projection: recon = g(512) @ doW(512,24576) + dob ----------
__global__ void __launch_bounds__(256)
final_kernel(const float* __restrict__ g, const float* __restrict__ W,
             const float* __restrict__ B, float* __restrict__ out)
{
    __shared__ float gs[512];
    const int t = threadIdx.x;
    gs[t]       = g[t];
    gs[t + 256] = g[t + 256];
    __syncthreads();
    const int j = (int)blockIdx.x * 256 + t;
    float a0=0,a1=0,a2=0,a3=0;
    #pragma unroll 4
    for (int k = 0; k < 512; k += 4) {
        a0 = fmaf(gs[k  ], W[(size_t)(k  )*24576 + j], a0);
        a1 = fmaf(gs[k+1], W[(size_t)(k+1)*24576 + j], a1);
        a2 = fmaf(gs[k+2], W[(size_t)(k+2)*24576 + j], a2);
        a3 = fmaf(gs[k+3], W[(size_t)(k+3)*24576 + j], a3);
    }
    out[j] = ((a0+a1)+(a2+a3)) + B[j];
}

extern "C" void kernel_launch(void* const* d_in, const int* in_sizes, int n_in,
                              void* d_out, int out_size, void* d_ws, size_t ws_size,
                              hipStream_t stream)
{
    (void)n_in; (void)out_size; (void)ws_size;
    const float* pts = (const float*)d_in[0];
    const float* eW0 = (const float*)d_in[1];
    const float* eb0 = (const float*)d_in[2];
    const float* eg0 = (const float*)d_in[3];
    const float* ee0 = (const float*)d_in[4];
    const float* eW1 = (const float*)d_in[5];
    const float* eb1 = (const float*)d_in[6];
    const float* eg1 = (const float*)d_in[7];
    const float* ee1 = (const float*)d_in[8];
    const float* eW2 = (const float*)d_in[9];
    const float* eb2 = (const float*)d_in[10];
    const float* eg2 = (const float*)d_in[11];
    const float* ee2 = (const float*)d_in[12];
    const float* oW  = (const float*)d_in[13];
    const float* ob  = (const float*)d_in[14];
    const float* cb  = (const float*)d_in[15];
    const float* dW0 = (const float*)d_in[16];
    const float* db0 = (const float*)d_in[17];
    const float* dg0 = (const float*)d_in[18];
    const float* de0 = (const float*)d_in[19];
    const float* dW1 = (const float*)d_in[20];
    const float* db1 = (const float*)d_in[21];
    const float* dg1 = (const float*)d_in[22];
    const float* de1 = (const float*)d_in[23];
    const float* dW2 = (const float*)d_in[24];
    const float* db2 = (const float*)d_in[25];
    const float* dg2 = (const float*)d_in[26];
    const float* de2 = (const float*)d_in[27];
    const float* doW = (const float*)d_in[28];
    const float* dob = (const float*)d_in[29];

    float* out = (float*)d_out;
    float* ws  = (float*)d_ws;
    const int N = in_sizes[0] / 3;

    float* part = ws;                 // NBLK*256 = 65536 floats
    float* ze   = ws + 262144;        // 256
    float* qp   = ws + 262400;        // 128 (64 x {val, idx})
    float* g0   = ws + 262528;        // 512
    float* g1   = ws + 263040;        // 512
    float* g2   = ws + 263552;        // 512

    enc_kernel<<<NBLK, 512, 0, stream>>>(pts, N,
        eW0, eb0, eg0, ee0, eW1, eb1, eg1, ee1, eW2, eb2, eg2, ee2, part);
    pool_ze_kernel<<<1, 256, 0, stream>>>(part, oW, ob, out + 24576, ze);
    quant_kernel<<<64, 256, 0, stream>>>(cb, ze, qp);
    argmin_d0_kernel<<<1, 512, 0, stream>>>(qp, cb, ze, dW0, db0, dg0, de0, out + 24832, g0);
    dec_layer_kernel<<<1, 512, 0, stream>>>(g0, dW1, db1, dg1, de1, g1);
    dec_layer_kernel<<<1, 512, 0, stream>>>(g1, dW2, db2, dg2, de2, g2);
    final_kernel<<<96, 256, 0, stream>>>(g2, doW, dob, out);
}

// Round 14
// 331.032 us; speedup vs baseline: 3.3636x; 3.3636x over previous
//
#include <hip/hip_runtime.h>
#include <math.h>

#define NBLK 256   // encoder blocks: 8 waves (512 thr), 1 block/CU (LDS-limited)

typedef float    f32x4 __attribute__((ext_vector_type(4)));
typedef _Float16 f16x4 __attribute__((ext_vector_type(4)));
typedef _Float16 f16x2 __attribute__((ext_vector_type(2)));
typedef _Float16 f16x8 __attribute__((ext_vector_type(8)));

// classic MFMA spelling (pre-gfx950 builtins have no underscore before the type)
#define MFMA16(A,B,C) __builtin_amdgcn_mfma_f32_16x16x16f16((A),(B),(C),0,0,0)

// ---------- math helpers ----------
__device__ __forceinline__ float fast_rcp(float x) {
#if __has_builtin(__builtin_amdgcn_rcpf)
    return __builtin_amdgcn_rcpf(x);
#else
    return 1.0f / x;
#endif
}

// exact GELU: 0.5*x*(1+erf(x/sqrt(2))), erf via Abramowitz-Stegun 7.1.26 (|err|<1.5e-7)
__device__ __forceinline__ float gelu_exact(float x) {
    float u  = x * 0.70710678118654752440f;
    float au = fabsf(u);
    float t  = fast_rcp(fmaf(0.3275911f, au, 1.0f));
    float p  = t * fmaf(t, fmaf(t, fmaf(t, fmaf(t, 1.061405429f, -1.453152027f),
                       1.421413741f), -0.284496736f), 0.254829592f);
    float e  = __expf(-(au * au));
    float er = fmaf(-p, e, 1.0f);
    er = copysignf(er, u);
    return 0.5f * x * (1.0f + er);
}

__device__ __forceinline__ f16x2 pk_from(float a, float b) {
#if __has_builtin(__builtin_amdgcn_cvt_pkrtz)
    auto r = __builtin_amdgcn_cvt_pkrtz(a, b);   // __fp16 ext_vector(2): same bits
    f16x2 out;
    __builtin_memcpy(&out, &r, sizeof(out));
    return out;
#else
    return (f16x2){(_Float16)a, (_Float16)b};
#endif
}

// ---------- fused encoder: zero-barrier MFMA, register-budgeted (r11 structure) ----------
// r11 verified at 299us (VGPR 124, no spill). r12/r13's all-register B-chain spilled
// (128-cap, 327MB writes) -> reverted. One tweak vs r11: the L2 pass-A park is a
// same-lane round-trip, so park packed f16x4 at [nt][lane] (b64 ops) instead of
// 64 scalar f16 DS ops per tile. No register increase, no layout change elsewhere.
// Each wave owns 16 points end-to-end (tile = 8x16 = 128 pts), full channels:
//   L0: 4 MFMAs (A from coords, K=16, k<3; no weight LDS reads)
//   L1: 32 MFMAs, acc1[8] in regs
//   L2: pass A (nt0-7, 64 MFMAs) -> packed f16 park + f32 stats;
//       pass B (nt8-15, 64 MFMAs) stays in regs; shuffle-reduce; normalize.
// LN fully in-wave (shfl_xor over l15). Activations in wave-private LDS
// (same-wave DS ordering -> NO barriers in the tile loop).
// Lane maps (m89 + r9/r11 HW-verified): A row=l%16,k=4*(l/16)+j; B col=l%16;
// D col=l&15 (=n), row=4*(l>>4)+reg (=m).
__global__ void __launch_bounds__(512, 1)
enc_kernel(const float* __restrict__ pts, int N,
           const float* __restrict__ W0, const float* __restrict__ B0,
           const float* __restrict__ G0, const float* __restrict__ E0,
           const float* __restrict__ W1, const float* __restrict__ B1,
           const float* __restrict__ G1, const float* __restrict__ E1,
           const float* __restrict__ W2, const float* __restrict__ B2,
           const float* __restrict__ G2, const float* __restrict__ E2,
           float* __restrict__ part)
{
    __shared__ __align__(16) _Float16 w1q[8*2*64*8];     // 16 KB  [nt][ks2][lane][8]
    __shared__ __align__(16) _Float16 w2q[16*4*64*8];    // 64 KB  [nt][ks2][lane][8]
    __shared__ __align__(16) _Float16 actL1[8][16*132];  // 33 KB  L1 acts (stride 132)
    __shared__ __align__(16) _Float16 scr[8][16*132];    // 33 KB  L0 acts (stride 68) / L2 packed park
    __shared__ __align__(16) float v1s[384];             // B1|G1|E1
    __shared__ __align__(16) float v2s[768];             // B2|G2|E2

    const int tid  = threadIdx.x;
    const int lane = tid & 63;
    const int wid  = tid >> 6;     // 0..7
    const int l15  = lane & 15;
    const int l4   = lane >> 4;    // 0..3

    // ---- one-time: pack W1/W2 into paired-ks B-fragment order ----
    #pragma unroll
    for (int e = 0; e < 2; ++e) {   // w1q: 8nt x 2ks2 x 64 = 1024 entries
        int idx = tid + e*512;
        int l = idx & 63, ks2 = (idx >> 6) & 1, nt = idx >> 7;
        f16x8 v;
        #pragma unroll
        for (int jj = 0; jj < 8; ++jj) {
            int ks = ks2*2 + (jj >> 2), j = jj & 3;
            int k  = ks*16 + ((l >> 4) << 2) + j;
            v[jj] = (_Float16)W1[k*128 + nt*16 + (l & 15)];
        }
        *(f16x8*)&w1q[idx*8] = v;
    }
    #pragma unroll
    for (int e = 0; e < 8; ++e) {   // w2q: 16nt x 4ks2 x 64 = 4096 entries
        int idx = tid + e*512;
        int l = idx & 63, ks2 = (idx >> 6) & 3, nt = idx >> 8;
        f16x8 v;
        #pragma unroll
        for (int jj = 0; jj < 8; ++jj) {
            int ks = ks2*2 + (jj >> 2), j = jj & 3;
            int k  = ks*16 + ((l >> 4) << 2) + j;
            v[jj] = (_Float16)W2[k*256 + nt*16 + (l & 15)];
        }
        *(f16x8*)&w2q[idx*8] = v;
    }
    if (tid < 128) { v1s[tid] = B1[tid]; v1s[128 + tid] = G1[tid]; v1s[256 + tid] = E1[tid]; }
    if (tid >= 256) {
        int c = tid - 256;
        v2s[c] = B2[c]; v2s[256 + c] = G2[c]; v2s[512 + c] = E2[c];
    }

    // ---- tile-invariant regs: W0 B-fragments + L0 bias/gain (ch = nt*16+l15) ----
    f16x4 w0f[4];
    float b0v[4], g0v[4], e0v[4];
    #pragma unroll
    for (int nt = 0; nt < 4; ++nt) {
        int ch = nt*16 + l15;
        #pragma unroll
        for (int j = 0; j < 4; ++j) {
            int k = l4*4 + j;
            w0f[nt][j] = (_Float16)((k < 3) ? W0[k*64 + ch] : 0.0f);
        }
        b0v[nt] = B0[ch]; g0v[nt] = G0[ch]; e0v[nt] = E0[ch];
    }
    __syncthreads();

    float run[16];
    #pragma unroll
    for (int nt = 0; nt < 16; ++nt) run[nt] = -INFINITY;

    const int tiles = (N + 127) >> 7;
    for (int t = blockIdx.x; t < tiles; t += NBLK) {
        const int pbase = t*128 + wid*16;          // this wave's 16 points
        // ---- L0: A built from coords (row = l15 = point, k = l4*4+j) ----
        f16x4 A0 = {(_Float16)0, (_Float16)0, (_Float16)0, (_Float16)0};
        {
            int p = pbase + l15;
            if (l4 == 0 && p < N) {
                A0[0] = (_Float16)pts[p*3];
                A0[1] = (_Float16)pts[p*3+1];
                A0[2] = (_Float16)pts[p*3+2];
            }
        }
        f32x4 acc0[4];
        #pragma unroll
        for (int nt = 0; nt < 4; ++nt) {
            acc0[nt] = (f32x4){b0v[nt], b0v[nt], b0v[nt], b0v[nt]};
            acc0[nt] = MFMA16(A0, w0f[nt], acc0[nt]);
        }
        {   // LN(64) in-wave + GELU -> scr rows (stride 68)
            f32x4 s4 = (acc0[0] + acc0[1]) + (acc0[2] + acc0[3]);
            f32x4 q4 = (acc0[0]*acc0[0] + acc0[1]*acc0[1]) + (acc0[2]*acc0[2] + acc0[3]*acc0[3]);
            #pragma unroll
            for (int m = 1; m < 16; m <<= 1)
                #pragma unroll
                for (int i = 0; i < 4; ++i) {
                    s4[i] += __shfl_xor(s4[i], m, 64);
                    q4[i] += __shfl_xor(q4[i], m, 64);
                }
            f32x4 mu, rs;
            #pragma unroll
            for (int i = 0; i < 4; ++i) {
                float m_ = s4[i] * (1.0f/64.0f);
                float v_ = q4[i] * (1.0f/64.0f) - m_*m_;
                mu[i] = m_; rs[i] = rsqrtf(v_ + 1e-5f);
            }
            #pragma unroll
            for (int nt = 0; nt < 4; ++nt)
                #pragma unroll
                for (int r = 0; r < 4; ++r) {
                    float v = fmaf((acc0[nt][r]-mu[r])*rs[r], g0v[nt], e0v[nt]);
                    scr[wid][(l4*4+r)*68 + nt*16 + l15] = (_Float16)gelu_exact(v);
                }
        }

        // ---- L1: 64 -> 128 (8 nt x 4 ks) ----
        f32x4 acc1[8];
        #pragma unroll
        for (int nt = 0; nt < 8; ++nt) {
            float b = v1s[nt*16 + l15];
            acc1[nt] = (f32x4){b, b, b, b};
        }
        #pragma unroll
        for (int ks2 = 0; ks2 < 2; ++ks2) {
            f16x4 Aa = *(const f16x4*)&scr[wid][l15*68 + (ks2*2+0)*16 + l4*4];
            f16x4 Ab = *(const f16x4*)&scr[wid][l15*68 + (ks2*2+1)*16 + l4*4];
            #pragma unroll
            for (int nt = 0; nt < 8; ++nt) {
                f16x8 bb = *(const f16x8*)&w1q[((nt*2 + ks2)*64 + lane)*8];
                f16x4 blo = __builtin_shufflevector(bb, bb, 0,1,2,3);
                f16x4 bhi = __builtin_shufflevector(bb, bb, 4,5,6,7);
                acc1[nt] = MFMA16(Aa, blo, acc1[nt]);
                acc1[nt] = MFMA16(Ab, bhi, acc1[nt]);
            }
        }
        {   // LN(128) in-wave + GELU -> actL1 rows (stride 132)
            f32x4 s4 = ((acc1[0]+acc1[1])+(acc1[2]+acc1[3])) + ((acc1[4]+acc1[5])+(acc1[6]+acc1[7]));
            f32x4 q4 = ((acc1[0]*acc1[0]+acc1[1]*acc1[1])+(acc1[2]*acc1[2]+acc1[3]*acc1[3]))
                     + ((acc1[4]*acc1[4]+acc1[5]*acc1[5])+(acc1[6]*acc1[6]+acc1[7]*acc1[7]));
            #pragma unroll
            for (int m = 1; m < 16; m <<= 1)
                #pragma unroll
                for (int i = 0; i < 4; ++i) {
                    s4[i] += __shfl_xor(s4[i], m, 64);
                    q4[i] += __shfl_xor(q4[i], m, 64);
                }
            f32x4 mu, rs;
            #pragma unroll
            for (int i = 0; i < 4; ++i) {
                float m_ = s4[i] * (1.0f/128.0f);
                float v_ = q4[i] * (1.0f/128.0f) - m_*m_;
                mu[i] = m_; rs[i] = rsqrtf(v_ + 1e-5f);
            }
            #pragma unroll
            for (int nt = 0; nt < 8; ++nt) {
                float g = v1s[128 + nt*16 + l15], e = v1s[256 + nt*16 + l15];
                #pragma unroll
                for (int r = 0; r < 4; ++r) {
                    float v = fmaf((acc1[nt][r]-mu[r])*rs[r], g, e);
                    actL1[wid][(l4*4+r)*132 + nt*16 + l15] = (_Float16)gelu_exact(v);
                }
            }
        }

        // ---- L2: 128 -> 256, two passes of 8 nt (register-budgeted) ----
        f32x4 sT = {0,0,0,0}, qT = {0,0,0,0};
        f32x4 acc2[8];
        // pass A: nt 0..7 -> packed f16 park (b64, same-lane round trip) + f32 stats
        #pragma unroll
        for (int nt = 0; nt < 8; ++nt) {
            float b = v2s[nt*16 + l15];
            acc2[nt] = (f32x4){b, b, b, b};
        }
        #pragma unroll
        for (int ks2 = 0; ks2 < 4; ++ks2) {
            f16x4 Aa = *(const f16x4*)&actL1[wid][l15*132 + (ks2*2+0)*16 + l4*4];
            f16x4 Ab = *(const f16x4*)&actL1[wid][l15*132 + (ks2*2+1)*16 + l4*4];
            #pragma unroll
            for (int nt = 0; nt < 8; ++nt) {
                f16x8 bb = *(const f16x8*)&w2q[((nt*4 + ks2)*64 + lane)*8];
                f16x4 blo = __builtin_shufflevector(bb, bb, 0,1,2,3);
                f16x4 bhi = __builtin_shufflevector(bb, bb, 4,5,6,7);
                acc2[nt] = MFMA16(Aa, blo, acc2[nt]);
                acc2[nt] = MFMA16(Ab, bhi, acc2[nt]);
            }
        }
        #pragma unroll
        for (int nt = 0; nt < 8; ++nt) {
            sT += acc2[nt];
            qT += acc2[nt]*acc2[nt];
            f16x2 lo = pk_from(acc2[nt][0], acc2[nt][1]);
            f16x2 hi = pk_from(acc2[nt][2], acc2[nt][3]);
            f16x4 pk = (f16x4){lo[0], lo[1], hi[0], hi[1]};
            *(f16x4*)&scr[wid][(nt*64 + lane)*4] = pk;   // b64 store
        }
        // pass B: nt 8..15 -> stays in regs
        #pragma unroll
        for (int nt = 0; nt < 8; ++nt) {
            float b = v2s[(nt+8)*16 + l15];
            acc2[nt] = (f32x4){b, b, b, b};
        }
        #pragma unroll
        for (int ks2 = 0; ks2 < 4; ++ks2) {
            f16x4 Aa = *(const f16x4*)&actL1[wid][l15*132 + (ks2*2+0)*16 + l4*4];
            f16x4 Ab = *(const f16x4*)&actL1[wid][l15*132 + (ks2*2+1)*16 + l4*4];
            #pragma unroll
            for (int nt = 0; nt < 8; ++nt) {
                f16x8 bb = *(const f16x8*)&w2q[(((nt+8)*4 + ks2)*64 + lane)*8];
                f16x4 blo = __builtin_shufflevector(bb, bb, 0,1,2,3);
                f16x4 bhi = __builtin_shufflevector(bb, bb, 4,5,6,7);
                acc2[nt] = MFMA16(Aa, blo, acc2[nt]);
                acc2[nt] = MFMA16(Ab, bhi, acc2[nt]);
            }
        }
        #pragma unroll
        for (int nt = 0; nt < 8; ++nt) {
            sT += acc2[nt];
            qT += acc2[nt]*acc2[nt];
        }
        {   // LN(256) reduce + GELU + masked running max
            #pragma unroll
            for (int m = 1; m < 16; m <<= 1)
                #pragma unroll
                for (int i = 0; i < 4; ++i) {
                    sT[i] += __shfl_xor(sT[i], m, 64);
                    qT[i] += __shfl_xor(qT[i], m, 64);
                }
            f32x4 mu, rs;
            bool pv[4];
            #pragma unroll
            for (int i = 0; i < 4; ++i) {
                float m_ = sT[i] * (1.0f/256.0f);
                float v_ = qT[i] * (1.0f/256.0f) - m_*m_;
                mu[i] = m_; rs[i] = rsqrtf(v_ + 1e-5f);
                pv[i] = (pbase + l4*4 + i) < N;
            }
            #pragma unroll
            for (int nt = 0; nt < 8; ++nt) {   // pass B channels (nt+8) from regs
                int ch = (nt+8)*16 + l15;
                float g = v2s[256 + ch], e = v2s[512 + ch];
                float rm = -INFINITY;
                #pragma unroll
                for (int r = 0; r < 4; ++r) {
                    float v = fmaf((acc2[nt][r]-mu[r])*rs[r], g, e);
                    v = gelu_exact(v);
                    rm = fmaxf(rm, pv[r] ? v : -INFINITY);
                }
                run[nt+8] = fmaxf(run[nt+8], rm);
            }
            #pragma unroll
            for (int nt = 0; nt < 8; ++nt) {   // pass A channels from packed park
                int ch = nt*16 + l15;
                float g = v2s[256 + ch], e = v2s[512 + ch];
                f16x4 pk = *(const f16x4*)&scr[wid][(nt*64 + lane)*4];
                float rm = -INFINITY;
                #pragma unroll
                for (int r = 0; r < 4; ++r) {
                    float raw = (float)pk[r];
                    float v = fmaf((raw-mu[r])*rs[r], g, e);
                    v = gelu_exact(v);
                    rm = fmaxf(rm, pv[r] ? v : -INFINITY);
                }
                run[nt] = fmaxf(run[nt], rm);
            }
        }
    }

    // ---------- epilogue: wave max merge via pm overlay on actL1 ----------
    __syncthreads();                       // all tile work done before overlaying
    float* pm = (float*)actL1;             // 8 KB region
    #pragma unroll
    for (int nt = 0; nt < 16; ++nt) {
        float v = run[nt];
        v = fmaxf(v, __shfl_xor(v, 16, 64));
        v = fmaxf(v, __shfl_xor(v, 32, 64));
        if (l4 == 0) pm[wid*256 + nt*16 + l15] = v;
    }
    __syncthreads();
    if (tid < 256) {
        float v = pm[tid];
        #pragma unroll
        for (int w = 1; w < 8; ++w) v = fmaxf(v, pm[w*256 + tid]);
        part[(size_t)blockIdx.x * 256 + tid] = v;
    }
}

// ---------- reduce partials -> pooled(256); z_e = pooled @ oW + ob ----------
__global__ void __launch_bounds__(256)
pool_ze_kernel(const float* __restrict__ part, const float* __restrict__ oW,
               const float* __restrict__ ob, float* __restrict__ out_ze,
               float* __restrict__ ws_ze)
{
    __shared__ float pooled[256];
    const int j = threadIdx.x;
    float m0 = -INFINITY, m1 = -INFINITY, m2 = -INFINITY, m3 = -INFINITY;
    for (int b = 0; b < NBLK; b += 4) {
        m0 = fmaxf(m0, part[(b+0)*256 + j]);
        m1 = fmaxf(m1, part[(b+1)*256 + j]);
        m2 = fmaxf(m2, part[(b+2)*256 + j]);
        m3 = fmaxf(m3, part[(b+3)*256 + j]);
    }
    pooled[j] = fmaxf(fmaxf(m0, m1), fmaxf(m2, m3));
    __syncthreads();
    float a0 = 0.f, a1 = 0.f;
    for (int k = 0; k < 256; k += 2) {
        a0 = fmaf(pooled[k],   oW[(k  )*256 + j], a0);
        a1 = fmaf(pooled[k+1], oW[(k+1)*256 + j], a1);
    }
    float z = (a0 + a1) + ob[j];
    out_ze[j] = z;
    ws_ze[j]  = z;
}

// ---------- distances over codebook + per-block argmin partials ----------
__global__ void __launch_bounds__(256)
quant_kernel(const float* __restrict__ cb, const float* __restrict__ ze,
             float* __restrict__ qpart)
{
    const int lane = threadIdx.x & 63;
    const int wid  = threadIdx.x >> 6;
    const int gw   = (int)blockIdx.x * 4 + wid;   // 256 waves total
    const float4* cb4 = (const float4*)cb;
    const float4* z4p = (const float4*)ze;
    const float4  z   = z4p[lane];

    float bv = INFINITY;
    int   bi = 0x7fffffff;
    for (int code = gw; code < 8192; code += 256) {
        float4 c = cb4[code*64 + lane];
        float d = c.x*c.x + c.y*c.y + c.z*c.z + c.w*c.w
                - 2.0f*(c.x*z.x + c.y*z.y + c.z*z.z + c.w*z.w);
        #pragma unroll
        for (int m = 1; m < 64; m <<= 1) d += __shfl_xor(d, m, 64);
        if (d < bv) { bv = d; bi = code; }   // per-wave codes ascending; strict < keeps first
    }
    __shared__ float sv[4];
    __shared__ int   si[4];
    if (lane == 0) { sv[wid] = bv; si[wid] = bi; }
    __syncthreads();
    if (threadIdx.x == 0) {
        float v = sv[0]; int i = si[0];
        for (int w = 1; w < 4; ++w)
            if (sv[w] < v || (sv[w] == v && si[w] < i)) { v = sv[w]; i = si[w]; }
        qpart[blockIdx.x*2]     = v;
        qpart[blockIdx.x*2 + 1] = __int_as_float(i);
    }
}

// ---------- decoder block body: x(KIN) @ W(KIN,512) + b -> LN(512) -> GELU ----------
template<int KIN>
__device__ __forceinline__ void dec_block_body(const float* xs, const float* __restrict__ W,
        const float* __restrict__ B, const float* __restrict__ G,
        const float* __restrict__ E, float* __restrict__ xout, float* red)
{
    const int j = threadIdx.x;  // 512 threads
    float a0=0,a1=0,a2=0,a3=0;
    for (int k = 0; k < KIN; k += 4) {
        a0 = fmaf(xs[k  ], W[(k  )*512 + j], a0);
        a1 = fmaf(xs[k+1], W[(k+1)*512 + j], a1);
        a2 = fmaf(xs[k+2], W[(k+2)*512 + j], a2);
        a3 = fmaf(xs[k+3], W[(k+3)*512 + j], a3);
    }
    float acc = ((a0+a1)+(a2+a3)) + B[j];
    float s = acc, q = acc*acc;
    #pragma unroll
    for (int m = 1; m < 64; m <<= 1) { s += __shfl_xor(s, m, 64); q += __shfl_xor(q, m, 64); }
    const int wid = j >> 6, lane = j & 63;
    if (lane == 0) { red[wid*2] = s; red[wid*2+1] = q; }
    __syncthreads();
    float ts = 0.f, tq = 0.f;
    #pragma unroll
    for (int w = 0; w < 8; ++w) { ts += red[w*2]; tq += red[w*2+1]; }
    float mu  = ts * (1.0f/512.0f);
    float var = tq * (1.0f/512.0f) - mu*mu;
    float v = fmaf((acc - mu) * rsqrtf(var + 1e-5f), G[j], E[j]);
    xout[j] = gelu_exact(v);
}

// ---------- final argmin + z_q + straight-through + decoder layer 0 ----------
__global__ void __launch_bounds__(512)
argmin_d0_kernel(const float* __restrict__ qpart, const float* __restrict__ cb,
                 const float* __restrict__ ze,
                 const float* __restrict__ W, const float* __restrict__ B,
                 const float* __restrict__ G, const float* __restrict__ E,
                 float* __restrict__ out_zq, float* __restrict__ xout)
{
    __shared__ float xs[256];
    __shared__ float red[16];
    __shared__ int   sidx;
    const int j = threadIdx.x;
    if (j == 0) {
        float bv = INFINITY; int bi = 0x7fffffff;
        for (int b = 0; b < 64; ++b) {
            float v = qpart[b*2];
            int   i = __float_as_int(qpart[b*2 + 1]);
            if (v < bv || (v == bv && i < bi)) { bv = v; bi = i; }
        }
        sidx = bi;
    }
    __syncthreads();
    const int idx = sidx;
    if (j < 256) {
        float zq = cb[(size_t)idx*256 + j];
        out_zq[j] = zq;
        float z = ze[j];
        xs[j] = z + (zq - z);   // straight-through forward, matching ref fp ops
    }
    __syncthreads();
    dec_block_body<256>(xs, W, B, G, E, xout, red);
}

__global__ void __launch_bounds__(512)
dec_layer_kernel(const float* __restrict__ xin, const float* __restrict__ W,
                 const float* __restrict__ B, const float* __restrict__ G,
                 const float* __restrict__ E, float* __restrict__ xout)
{
    __shared__ float xs[512];
    __shared__ float red[16];
    xs[threadIdx.x] = xin[threadIdx.x];
    __syncthreads();
    dec_block_body<512>(xs, W, B, G, E, xout, red);
}

// ---------- final projection: recon = g(512) @ doW(512,24576) + dob ----------
__global__ void __launch_bounds__(256)
final_kernel(const float* __restrict__ g, const float* __restrict__ W,
             const float* __restrict__ B, float* __restrict__ out)
{
    __shared__ float gs[512];
    const int t = threadIdx.x;
    gs[t]       = g[t];
    gs[t + 256] = g[t + 256];
    __syncthreads();
    const int j = (int)blockIdx.x * 256 + t;
    float a0=0,a1=0,a2=0,a3=0;
    #pragma unroll 4
    for (int k = 0; k < 512; k += 4) {
        a0 = fmaf(gs[k  ], W[(size_t)(k  )*24576 + j], a0);
        a1 = fmaf(gs[k+1], W[(size_t)(k+1)*24576 + j], a1);
        a2 = fmaf(gs[k+2], W[(size_t)(k+2)*24576 + j], a2);
        a3 = fmaf(gs[k+3], W[(size_t)(k+3)*24576 + j], a3);
    }
    out[j] = ((a0+a1)+(a2+a3)) + B[j];
}

extern "C" void kernel_launch(void* const* d_in, const int* in_sizes, int n_in,
                              void* d_out, int out_size, void* d_ws, size_t ws_size,
                              hipStream_t stream)
{
    (void)n_in; (void)out_size; (void)ws_size;
    const float* pts = (const float*)d_in[0];
    const float* eW0 = (const float*)d_in[1];
    const float* eb0 = (const float*)d_in[2];
    const float* eg0 = (const float*)d_in[3];
    const float* ee0 = (const float*)d_in[4];
    const float* eW1 = (const float*)d_in[5];
    const float* eb1 = (const float*)d_in[6];
    const float* eg1 = (const float*)d_in[7];
    const float* ee1 = (const float*)d_in[8];
    const float* eW2 = (const float*)d_in[9];
    const float* eb2 = (const float*)d_in[10];
    const float* eg2 = (const float*)d_in[11];
    const float* ee2 = (const float*)d_in[12];
    const float* oW  = (const float*)d_in[13];
    const float* ob  = (const float*)d_in[14];
    const float* cb  = (const float*)d_in[15];
    const float* dW0 = (const float*)d_in[16];
    const float* db0 = (const float*)d_in[17];
    const float* dg0 = (const float*)d_in[18];
    const float* de0 = (const float*)d_in[19];
    const float* dW1 = (const float*)d_in[20];
    const float* db1 = (const float*)d_in[21];
    const float* dg1 = (const float*)d_in[22];
    const float* de1 = (const float*)d_in[23];
    const float* dW2 = (const float*)d_in[24];
    const float* db2 = (const float*)d_in[25];
    const float* dg2 = (const float*)d_in[26];
    const float* de2 = (const float*)d_in[27];
    const float* doW = (const float*)d_in[28];
    const float* dob = (const float*)d_in[29];

    float* out = (float*)d_out;
    float* ws  = (float*)d_ws;
    const int N = in_sizes[0] / 3;

    float* part = ws;                 // NBLK*256 = 65536 floats
    float* ze   = ws + 262144;        // 256
    float* qp   = ws + 262400;        // 128 (64 x {val, idx})
    float* g0   = ws + 262528;        // 512
    float* g1   = ws + 263040;        // 512
    float* g2   = ws + 263552;        // 512

    enc_kernel<<<NBLK, 512, 0, stream>>>(pts, N,
        eW0, eb0, eg0, ee0, eW1, eb1, eg1, ee1, eW2, eb2, eg2, ee2, part);
    pool_ze_kernel<<<1, 256, 0, stream>>>(part, oW, ob, out + 24576, ze);
    quant_kernel<<<64, 256, 0, stream>>>(cb, ze, qp);
    argmin_d0_kernel<<<1, 512, 0, stream>>>(qp, cb, ze, dW0, db0, dg0, de0, out + 24832, g0);
    dec_layer_kernel<<<1, 512, 0, stream>>>(g0, dW1, db1, dg1, de1, g1);
    dec_layer_kernel<<<1, 512, 0, stream>>>(g1, dW2, db2, dg2, de2, g2);
    final_kernel<<<96, 256, 0, stream>>>(g2, doW, dob, out);
}

// Round 16
// 329.558 us; speedup vs baseline: 3.3787x; 1.0045x over previous
//
#include <hip/hip_runtime.h>
#include <math.h>

#define NBLK 256   // encoder blocks: 8 waves (512 thr), 1 block/CU (LDS-limited)

typedef float    f32x4 __attribute__((ext_vector_type(4)));
typedef _Float16 f16x4 __attribute__((ext_vector_type(4)));
typedef _Float16 f16x2 __attribute__((ext_vector_type(2)));
typedef _Float16 f16x8 __attribute__((ext_vector_type(8)));

// classic MFMA spelling (pre-gfx950 builtins have no underscore before the type)
#define MFMA16(A,B,C) __builtin_amdgcn_mfma_f32_16x16x16f16((A),(B),(C),0,0,0)

// ---------- math helpers ----------
__device__ __forceinline__ float fast_rcp(float x) {
#if __has_builtin(__builtin_amdgcn_rcpf)
    return __builtin_amdgcn_rcpf(x);
#else
    return 1.0f / x;
#endif
}

// exact GELU: 0.5*x*(1+erf(x/sqrt(2))), erf via Abramowitz-Stegun 7.1.26 (|err|<1.5e-7)
__device__ __forceinline__ float gelu_exact(float x) {
    float u  = x * 0.70710678118654752440f;
    float au = fabsf(u);
    float t  = fast_rcp(fmaf(0.3275911f, au, 1.0f));
    float p  = t * fmaf(t, fmaf(t, fmaf(t, fmaf(t, 1.061405429f, -1.453152027f),
                       1.421413741f), -0.284496736f), 0.254829592f);
    float e  = __expf(-(au * au));
    float er = fmaf(-p, e, 1.0f);
    er = copysignf(er, u);
    return 0.5f * x * (1.0f + er);
}

__device__ __forceinline__ f16x2 pk_from(float a, float b) {
#if __has_builtin(__builtin_amdgcn_cvt_pkrtz)
    auto r = __builtin_amdgcn_cvt_pkrtz(a, b);   // __fp16 ext_vector(2): same bits
    f16x2 out;
    __builtin_memcpy(&out, &r, sizeof(out));
    return out;
#else
    return (f16x2){(_Float16)a, (_Float16)b};
#endif
}

// ---------- fused encoder: zero-barrier MFMA, register-budgeted (r11/r14 structure) ----------
// Verified 299-304us steady (VGPR 124-128, no spill). Structure is at its practical
// ceiling: occupancy capped at 2 waves/SIMD by LDS (W2 f16 64KB prevents 2-block
// residency; fp8 weights risk argmin flips), VGPR capped at 128 (B-chain spilled
// twice, r10/r13). Enc untouched this round.
__global__ void __launch_bounds__(512, 1)
enc_kernel(const float* __restrict__ pts, int N,
           const float* __restrict__ W0, const float* __restrict__ B0,
           const float* __restrict__ G0, const float* __restrict__ E0,
           const float* __restrict__ W1, const float* __restrict__ B1,
           const float* __restrict__ G1, const float* __restrict__ E1,
           const float* __restrict__ W2, const float* __restrict__ B2,
           const float* __restrict__ G2, const float* __restrict__ E2,
           float* __restrict__ part)
{
    __shared__ __align__(16) _Float16 w1q[8*2*64*8];     // 16 KB  [nt][ks2][lane][8]
    __shared__ __align__(16) _Float16 w2q[16*4*64*8];    // 64 KB  [nt][ks2][lane][8]
    __shared__ __align__(16) _Float16 actL1[8][16*132];  // 33 KB  L1 acts (stride 132)
    __shared__ __align__(16) _Float16 scr[8][16*132];    // 33 KB  L0 acts / L2 packed park
    __shared__ __align__(16) float v1s[384];             // B1|G1|E1
    __shared__ __align__(16) float v2s[768];             // B2|G2|E2

    const int tid  = threadIdx.x;
    const int lane = tid & 63;
    const int wid  = tid >> 6;     // 0..7
    const int l15  = lane & 15;
    const int l4   = lane >> 4;    // 0..3

    // ---- one-time: pack W1/W2 into paired-ks B-fragment order ----
    #pragma unroll
    for (int e = 0; e < 2; ++e) {   // w1q: 8nt x 2ks2 x 64 = 1024 entries
        int idx = tid + e*512;
        int l = idx & 63, ks2 = (idx >> 6) & 1, nt = idx >> 7;
        f16x8 v;
        #pragma unroll
        for (int jj = 0; jj < 8; ++jj) {
            int ks = ks2*2 + (jj >> 2), j = jj & 3;
            int k  = ks*16 + ((l >> 4) << 2) + j;
            v[jj] = (_Float16)W1[k*128 + nt*16 + (l & 15)];
        }
        *(f16x8*)&w1q[idx*8] = v;
    }
    #pragma unroll
    for (int e = 0; e < 8; ++e) {   // w2q: 16nt x 4ks2 x 64 = 4096 entries
        int idx = tid + e*512;
        int l = idx & 63, ks2 = (idx >> 6) & 3, nt = idx >> 8;
        f16x8 v;
        #pragma unroll
        for (int jj = 0; jj < 8; ++jj) {
            int ks = ks2*2 + (jj >> 2), j = jj & 3;
            int k  = ks*16 + ((l >> 4) << 2) + j;
            v[jj] = (_Float16)W2[k*256 + nt*16 + (l & 15)];
        }
        *(f16x8*)&w2q[idx*8] = v;
    }
    if (tid < 128) { v1s[tid] = B1[tid]; v1s[128 + tid] = G1[tid]; v1s[256 + tid] = E1[tid]; }
    if (tid >= 256) {
        int c = tid - 256;
        v2s[c] = B2[c]; v2s[256 + c] = G2[c]; v2s[512 + c] = E2[c];
    }

    // ---- tile-invariant regs: W0 B-fragments + L0 bias/gain (ch = nt*16+l15) ----
    f16x4 w0f[4];
    float b0v[4], g0v[4], e0v[4];
    #pragma unroll
    for (int nt = 0; nt < 4; ++nt) {
        int ch = nt*16 + l15;
        #pragma unroll
        for (int j = 0; j < 4; ++j) {
            int k = l4*4 + j;
            w0f[nt][j] = (_Float16)((k < 3) ? W0[k*64 + ch] : 0.0f);
        }
        b0v[nt] = B0[ch]; g0v[nt] = G0[ch]; e0v[nt] = E0[ch];
    }
    __syncthreads();

    float run[16];
    #pragma unroll
    for (int nt = 0; nt < 16; ++nt) run[nt] = -INFINITY;

    const int tiles = (N + 127) >> 7;
    for (int t = blockIdx.x; t < tiles; t += NBLK) {
        const int pbase = t*128 + wid*16;          // this wave's 16 points
        // ---- L0: A built from coords (row = l15 = point, k = l4*4+j) ----
        f16x4 A0 = {(_Float16)0, (_Float16)0, (_Float16)0, (_Float16)0};
        {
            int p = pbase + l15;
            if (l4 == 0 && p < N) {
                A0[0] = (_Float16)pts[p*3];
                A0[1] = (_Float16)pts[p*3+1];
                A0[2] = (_Float16)pts[p*3+2];
            }
        }
        f32x4 acc0[4];
        #pragma unroll
        for (int nt = 0; nt < 4; ++nt) {
            acc0[nt] = (f32x4){b0v[nt], b0v[nt], b0v[nt], b0v[nt]};
            acc0[nt] = MFMA16(A0, w0f[nt], acc0[nt]);
        }
        {   // LN(64) in-wave + GELU -> scr rows (stride 68)
            f32x4 s4 = (acc0[0] + acc0[1]) + (acc0[2] + acc0[3]);
            f32x4 q4 = (acc0[0]*acc0[0] + acc0[1]*acc0[1]) + (acc0[2]*acc0[2] + acc0[3]*acc0[3]);
            #pragma unroll
            for (int m = 1; m < 16; m <<= 1)
                #pragma unroll
                for (int i = 0; i < 4; ++i) {
                    s4[i] += __shfl_xor(s4[i], m, 64);
                    q4[i] += __shfl_xor(q4[i], m, 64);
                }
            f32x4 mu, rs;
            #pragma unroll
            for (int i = 0; i < 4; ++i) {
                float m_ = s4[i] * (1.0f/64.0f);
                float v_ = q4[i] * (1.0f/64.0f) - m_*m_;
                mu[i] = m_; rs[i] = rsqrtf(v_ + 1e-5f);
            }
            #pragma unroll
            for (int nt = 0; nt < 4; ++nt)
                #pragma unroll
                for (int r = 0; r < 4; ++r) {
                    float v = fmaf((acc0[nt][r]-mu[r])*rs[r], g0v[nt], e0v[nt]);
                    scr[wid][(l4*4+r)*68 + nt*16 + l15] = (_Float16)gelu_exact(v);
                }
        }

        // ---- L1: 64 -> 128 (8 nt x 4 ks) ----
        f32x4 acc1[8];
        #pragma unroll
        for (int nt = 0; nt < 8; ++nt) {
            float b = v1s[nt*16 + l15];
            acc1[nt] = (f32x4){b, b, b, b};
        }
        #pragma unroll
        for (int ks2 = 0; ks2 < 2; ++ks2) {
            f16x4 Aa = *(const f16x4*)&scr[wid][l15*68 + (ks2*2+0)*16 + l4*4];
            f16x4 Ab = *(const f16x4*)&scr[wid][l15*68 + (ks2*2+1)*16 + l4*4];
            #pragma unroll
            for (int nt = 0; nt < 8; ++nt) {
                f16x8 bb = *(const f16x8*)&w1q[((nt*2 + ks2)*64 + lane)*8];
                f16x4 blo = __builtin_shufflevector(bb, bb, 0,1,2,3);
                f16x4 bhi = __builtin_shufflevector(bb, bb, 4,5,6,7);
                acc1[nt] = MFMA16(Aa, blo, acc1[nt]);
                acc1[nt] = MFMA16(Ab, bhi, acc1[nt]);
            }
        }
        {   // LN(128) in-wave + GELU -> actL1 rows (stride 132)
            f32x4 s4 = ((acc1[0]+acc1[1])+(acc1[2]+acc1[3])) + ((acc1[4]+acc1[5])+(acc1[6]+acc1[7]));
            f32x4 q4 = ((acc1[0]*acc1[0]+acc1[1]*acc1[1])+(acc1[2]*acc1[2]+acc1[3]*acc1[3]))
                     + ((acc1[4]*acc1[4]+acc1[5]*acc1[5])+(acc1[6]*acc1[6]+acc1[7]*acc1[7]));
            #pragma unroll
            for (int m = 1; m < 16; m <<= 1)
                #pragma unroll
                for (int i = 0; i < 4; ++i) {
                    s4[i] += __shfl_xor(s4[i], m, 64);
                    q4[i] += __shfl_xor(q4[i], m, 64);
                }
            f32x4 mu, rs;
            #pragma unroll
            for (int i = 0; i < 4; ++i) {
                float m_ = s4[i] * (1.0f/128.0f);
                float v_ = q4[i] * (1.0f/128.0f) - m_*m_;
                mu[i] = m_; rs[i] = rsqrtf(v_ + 1e-5f);
            }
            #pragma unroll
            for (int nt = 0; nt < 8; ++nt) {
                float g = v1s[128 + nt*16 + l15], e = v1s[256 + nt*16 + l15];
                #pragma unroll
                for (int r = 0; r < 4; ++r) {
                    float v = fmaf((acc1[nt][r]-mu[r])*rs[r], g, e);
                    actL1[wid][(l4*4+r)*132 + nt*16 + l15] = (_Float16)gelu_exact(v);
                }
            }
        }

        // ---- L2: 128 -> 256, two passes of 8 nt (register-budgeted) ----
        f32x4 sT = {0,0,0,0}, qT = {0,0,0,0};
        f32x4 acc2[8];
        // pass A: nt 0..7 -> packed f16 park (b64, same-lane round trip) + f32 stats
        #pragma unroll
        for (int nt = 0; nt < 8; ++nt) {
            float b = v2s[nt*16 + l15];
            acc2[nt] = (f32x4){b, b, b, b};
        }
        #pragma unroll
        for (int ks2 = 0; ks2 < 4; ++ks2) {
            f16x4 Aa = *(const f16x4*)&actL1[wid][l15*132 + (ks2*2+0)*16 + l4*4];
            f16x4 Ab = *(const f16x4*)&actL1[wid][l15*132 + (ks2*2+1)*16 + l4*4];
            #pragma unroll
            for (int nt = 0; nt < 8; ++nt) {
                f16x8 bb = *(const f16x8*)&w2q[((nt*4 + ks2)*64 + lane)*8];
                f16x4 blo = __builtin_shufflevector(bb, bb, 0,1,2,3);
                f16x4 bhi = __builtin_shufflevector(bb, bb, 4,5,6,7);
                acc2[nt] = MFMA16(Aa, blo, acc2[nt]);
                acc2[nt] = MFMA16(Ab, bhi, acc2[nt]);
            }
        }
        #pragma unroll
        for (int nt = 0; nt < 8; ++nt) {
            sT += acc2[nt];
            qT += acc2[nt]*acc2[nt];
            f16x2 lo = pk_from(acc2[nt][0], acc2[nt][1]);
            f16x2 hi = pk_from(acc2[nt][2], acc2[nt][3]);
            f16x4 pk = (f16x4){lo[0], lo[1], hi[0], hi[1]};
            *(f16x4*)&scr[wid][(nt*64 + lane)*4] = pk;   // b64 store
        }
        // pass B: nt 8..15 -> stays in regs
        #pragma unroll
        for (int nt = 0; nt < 8; ++nt) {
            float b = v2s[(nt+8)*16 + l15];
            acc2[nt] = (f32x4){b, b, b, b};
        }
        #pragma unroll
        for (int ks2 = 0; ks2 < 4; ++ks2) {
            f16x4 Aa = *(const f16x4*)&actL1[wid][l15*132 + (ks2*2+0)*16 + l4*4];
            f16x4 Ab = *(const f16x4*)&actL1[wid][l15*132 + (ks2*2+1)*16 + l4*4];
            #pragma unroll
            for (int nt = 0; nt < 8; ++nt) {
                f16x8 bb = *(const f16x8*)&w2q[(((nt+8)*4 + ks2)*64 + lane)*8];
                f16x4 blo = __builtin_shufflevector(bb, bb, 0,1,2,3);
                f16x4 bhi = __builtin_shufflevector(bb, bb, 4,5,6,7);
                acc2[nt] = MFMA16(Aa, blo, acc2[nt]);
                acc2[nt] = MFMA16(Ab, bhi, acc2[nt]);
            }
        }
        #pragma unroll
        for (int nt = 0; nt < 8; ++nt) {
            sT += acc2[nt];
            qT += acc2[nt]*acc2[nt];
        }
        {   // LN(256) reduce + GELU + masked running max
            #pragma unroll
            for (int m = 1; m < 16; m <<= 1)
                #pragma unroll
                for (int i = 0; i < 4; ++i) {
                    sT[i] += __shfl_xor(sT[i], m, 64);
                    qT[i] += __shfl_xor(qT[i], m, 64);
                }
            f32x4 mu, rs;
            bool pv[4];
            #pragma unroll
            for (int i = 0; i < 4; ++i) {
                float m_ = sT[i] * (1.0f/256.0f);
                float v_ = qT[i] * (1.0f/256.0f) - m_*m_;
                mu[i] = m_; rs[i] = rsqrtf(v_ + 1e-5f);
                pv[i] = (pbase + l4*4 + i) < N;
            }
            #pragma unroll
            for (int nt = 0; nt < 8; ++nt) {   // pass B channels (nt+8) from regs
                int ch = (nt+8)*16 + l15;
                float g = v2s[256 + ch], e = v2s[512 + ch];
                float rm = -INFINITY;
                #pragma unroll
                for (int r = 0; r < 4; ++r) {
                    float v = fmaf((acc2[nt][r]-mu[r])*rs[r], g, e);
                    v = gelu_exact(v);
                    rm = fmaxf(rm, pv[r] ? v : -INFINITY);
                }
                run[nt+8] = fmaxf(run[nt+8], rm);
            }
            #pragma unroll
            for (int nt = 0; nt < 8; ++nt) {   // pass A channels from packed park
                int ch = nt*16 + l15;
                float g = v2s[256 + ch], e = v2s[512 + ch];
                f16x4 pk = *(const f16x4*)&scr[wid][(nt*64 + lane)*4];
                float rm = -INFINITY;
                #pragma unroll
                for (int r = 0; r < 4; ++r) {
                    float raw = (float)pk[r];
                    float v = fmaf((raw-mu[r])*rs[r], g, e);
                    v = gelu_exact(v);
                    rm = fmaxf(rm, pv[r] ? v : -INFINITY);
                }
                run[nt] = fmaxf(run[nt], rm);
            }
        }
    }

    // ---------- epilogue: wave max merge via pm overlay on actL1 ----------
    __syncthreads();                       // all tile work done before overlaying
    float* pm = (float*)actL1;             // 8 KB region
    #pragma unroll
    for (int nt = 0; nt < 16; ++nt) {
        float v = run[nt];
        v = fmaxf(v, __shfl_xor(v, 16, 64));
        v = fmaxf(v, __shfl_xor(v, 32, 64));
        if (l4 == 0) pm[wid*256 + nt*16 + l15] = v;
    }
    __syncthreads();
    if (tid < 256) {
        float v = pm[tid];
        #pragma unroll
        for (int w = 1; w < 8; ++w) v = fmaxf(v, pm[w*256 + tid]);
        part[(size_t)blockIdx.x * 256 + tid] = v;
    }
}

// ---------- reduce partials -> pooled(256); z_e = pooled @ oW + ob ----------
__global__ void __launch_bounds__(256)
pool_ze_kernel(const float* __restrict__ part, const float* __restrict__ oW,
               const float* __restrict__ ob, float* __restrict__ out_ze,
               float* __restrict__ ws_ze)
{
    __shared__ float pooled[256];
    const int j = threadIdx.x;
    float m0 = -INFINITY, m1 = -INFINITY, m2 = -INFINITY, m3 = -INFINITY;
    for (int b = 0; b < NBLK; b += 4) {
        m0 = fmaxf(m0, part[(b+0)*256 + j]);
        m1 = fmaxf(m1, part[(b+1)*256 + j]);
        m2 = fmaxf(m2, part[(b+2)*256 + j]);
        m3 = fmaxf(m3, part[(b+3)*256 + j]);
    }
    pooled[j] = fmaxf(fmaxf(m0, m1), fmaxf(m2, m3));
    __syncthreads();
    float a0 = 0.f, a1 = 0.f;
    for (int k = 0; k < 256; k += 2) {
        a0 = fmaf(pooled[k],   oW[(k  )*256 + j], a0);
        a1 = fmaf(pooled[k+1], oW[(k+1)*256 + j], a1);
    }
    float z = (a0 + a1) + ob[j];
    out_ze[j] = z;
    ws_ze[j]  = z;
}

// ---------- distances over codebook + per-block argmin partials ----------
__global__ void __launch_bounds__(256)
quant_kernel(const float* __restrict__ cb, const float* __restrict__ ze,
             float* __restrict__ qpart)
{
    const int lane = threadIdx.x & 63;
    const int wid  = threadIdx.x >> 6;
    const int gw   = (int)blockIdx.x * 4 + wid;   // 256 waves total
    const float4* cb4 = (const float4*)cb;
    const float4* z4p = (const float4*)ze;
    const float4  z   = z4p[lane];

    float bv = INFINITY;
    int   bi = 0x7fffffff;
    for (int code = gw; code < 8192; code += 256) {
        float4 c = cb4[code*64 + lane];
        float d = c.x*c.x + c.y*c.y + c.z*c.z + c.w*c.w
                - 2.0f*(c.x*z.x + c.y*z.y + c.z*z.z + c.w*z.w);
        #pragma unroll
        for (int m = 1; m < 64; m <<= 1) d += __shfl_xor(d, m, 64);
        if (d < bv) { bv = d; bi = code; }   // per-wave codes ascending; strict < keeps first
    }
    __shared__ float sv[4];
    __shared__ int   si[4];
    if (lane == 0) { sv[wid] = bv; si[wid] = bi; }
    __syncthreads();
    if (threadIdx.x == 0) {
        float v = sv[0]; int i = si[0];
        for (int w = 1; w < 4; ++w)
            if (sv[w] < v || (sv[w] == v && si[w] < i)) { v = sv[w]; i = si[w]; }
        qpart[blockIdx.x*2]     = v;
        qpart[blockIdx.x*2 + 1] = __int_as_float(i);
    }
}

// ---------- decoder block body: x(KIN) @ W(KIN,512) + b -> LN(512) -> GELU ----------
template<int KIN>
__device__ __forceinline__ void dec_block_body(const float* xs, const float* __restrict__ W,
        const float* __restrict__ B, const float* __restrict__ G,
        const float* __restrict__ E, float* __restrict__ xout, float* red)
{
    const int j = threadIdx.x;  // 512 threads
    float a0=0,a1=0,a2=0,a3=0;
    for (int k = 0; k < KIN; k += 4) {
        a0 = fmaf(xs[k  ], W[(k  )*512 + j], a0);
        a1 = fmaf(xs[k+1], W[(k+1)*512 + j], a1);
        a2 = fmaf(xs[k+2], W[(k+2)*512 + j], a2);
        a3 = fmaf(xs[k+3], W[(k+3)*512 + j], a3);
    }
    float acc = ((a0+a1)+(a2+a3)) + B[j];
    float s = acc, q = acc*acc;
    #pragma unroll
    for (int m = 1; m < 64; m <<= 1) { s += __shfl_xor(s, m, 64); q += __shfl_xor(q, m, 64); }
    const int wid = j >> 6, lane = j & 63;
    if (lane == 0) { red[wid*2] = s; red[wid*2+1] = q; }
    __syncthreads();
    float ts = 0.f, tq = 0.f;
    #pragma unroll
    for (int w = 0; w < 8; ++w) { ts += red[w*2]; tq += red[w*2+1]; }
    float mu  = ts * (1.0f/512.0f);
    float var = tq * (1.0f/512.0f) - mu*mu;
    float v = fmaf((acc - mu) * rsqrtf(var + 1e-5f), G[j], E[j]);
    xout[j] = gelu_exact(v);
}

// ---------- fused tail: argmin + z_q + straight-through + decoder L0+L1+L2 ----------
// Three former 1-block kernels fused (phases split by __syncthreads, ping-pong
// shared buffers) - saves 2 launches (~6-10us of launch+drain).
__global__ void __launch_bounds__(512)
tail_kernel(const float* __restrict__ qpart, const float* __restrict__ cb,
            const float* __restrict__ ze,
            const float* __restrict__ W0d, const float* __restrict__ B0d,
            const float* __restrict__ G0d, const float* __restrict__ E0d,
            const float* __restrict__ W1d, const float* __restrict__ B1d,
            const float* __restrict__ G1d, const float* __restrict__ E1d,
            const float* __restrict__ W2d, const float* __restrict__ B2d,
            const float* __restrict__ G2d, const float* __restrict__ E2d,
            float* __restrict__ out_zq, float* __restrict__ g2_out)
{
    __shared__ float xa[512];
    __shared__ float xb[512];
    __shared__ float red[16];
    __shared__ int   sidx;
    const int j = threadIdx.x;

    // phase 0: final argmin
    if (j == 0) {
        float bv = INFINITY; int bi = 0x7fffffff;
        for (int b = 0; b < 64; ++b) {
            float v = qpart[b*2];
            int   i = __float_as_int(qpart[b*2 + 1]);
            if (v < bv || (v == bv && i < bi)) { bv = v; bi = i; }
        }
        sidx = bi;
    }
    __syncthreads();
    const int idx = sidx;

    // phase 1: z_q + straight-through -> xa[0:256); decoder L0 (256 -> 512) -> xb
    if (j < 256) {
        float zq = cb[(size_t)idx*256 + j];
        out_zq[j] = zq;
        float z = ze[j];
        xa[j] = z + (zq - z);   // straight-through forward, matching ref fp ops
    }
    __syncthreads();
    dec_block_body<256>(xa, W0d, B0d, G0d, E0d, xb, red);
    __syncthreads();

    // phase 2: decoder L1 (512 -> 512) -> xa
    dec_block_body<512>(xb, W1d, B1d, G1d, E1d, xa, red);
    __syncthreads();

    // phase 3: decoder L2 (512 -> 512) -> xb -> global
    dec_block_body<512>(xa, W2d, B2d, G2d, E2d, xb, red);
    __syncthreads();
    g2_out[j] = xb[j];
}

// ---------- final projection: recon = g(512) @ doW(512,24576) + dob ----------
__global__ void __launch_bounds__(256)
final_kernel(const float* __restrict__ g, const float* __restrict__ W,
             const float* __restrict__ B, float* __restrict__ out)
{
    __shared__ float gs[512];
    const int t = threadIdx.x;
    gs[t]       = g[t];
    gs[t + 256] = g[t + 256];
    __syncthreads();
    const int j = (int)blockIdx.x * 256 + t;
    float a0=0,a1=0,a2=0,a3=0;
    #pragma unroll 4
    for (int k = 0; k < 512; k += 4) {
        a0 = fmaf(gs[k  ], W[(size_t)(k  )*24576 + j], a0);
        a1 = fmaf(gs[k+1], W[(size_t)(k+1)*24576 + j], a1);
        a2 = fmaf(gs[k+2], W[(size_t)(k+2)*24576 + j], a2);
        a3 = fmaf(gs[k+3], W[(size_t)(k+3)*24576 + j], a3);
    }
    out[j] = ((a0+a1)+(a2+a3)) + B[j];
}

extern "C" void kernel_launch(void* const* d_in, const int* in_sizes, int n_in,
                              void* d_out, int out_size, void* d_ws, size_t ws_size,
                              hipStream_t stream)
{
    (void)n_in; (void)out_size; (void)ws_size;
    const float* pts = (const float*)d_in[0];
    const float* eW0 = (const float*)d_in[1];
    const float* eb0 = (const float*)d_in[2];
    const float* eg0 = (const float*)d_in[3];
    const float* ee0 = (const float*)d_in[4];
    const float* eW1 = (const float*)d_in[5];
    const float* eb1 = (const float*)d_in[6];
    const float* eg1 = (const float*)d_in[7];
    const float* ee1 = (const float*)d_in[8];
    const float* eW2 = (const float*)d_in[9];
    const float* eb2 = (const float*)d_in[10];
    const float* eg2 = (const float*)d_in[11];
    const float* ee2 = (const float*)d_in[12];
    const float* oW  = (const float*)d_in[13];
    const float* ob  = (const float*)d_in[14];
    const float* cb  = (const float*)d_in[15];
    const float* dW0 = (const float*)d_in[16];
    const float* db0 = (const float*)d_in[17];
    const float* dg0 = (const float*)d_in[18];
    const float* de0 = (const float*)d_in[19];
    const float* dW1 = (const float*)d_in[20];
    const float* db1 = (const float*)d_in[21];
    const float* dg1 = (const float*)d_in[22];
    const float* de1 = (const float*)d_in[23];
    const float* dW2 = (const float*)d_in[24];
    const float* db2 = (const float*)d_in[25];
    const float* dg2 = (const float*)d_in[26];
    const float* de2 = (const float*)d_in[27];
    const float* doW = (const float*)d_in[28];
    const float* dob = (const float*)d_in[29];

    float* out = (float*)d_out;
    float* ws  = (float*)d_ws;
    const int N = in_sizes[0] / 3;

    float* part = ws;                 // NBLK*256 = 65536 floats
    float* ze   = ws + 262144;        // 256
    float* qp   = ws + 262400;        // 128 (64 x {val, idx})
    float* g2   = ws + 263552;        // 512

    enc_kernel<<<NBLK, 512, 0, stream>>>(pts, N,
        eW0, eb0, eg0, ee0, eW1, eb1, eg1, ee1, eW2, eb2, eg2, ee2, part);
    pool_ze_kernel<<<1, 256, 0, stream>>>(part, oW, ob, out + 24576, ze);
    quant_kernel<<<64, 256, 0, stream>>>(cb, ze, qp);
    tail_kernel<<<1, 512, 0, stream>>>(qp, cb, ze,
        dW0, db0, dg0, de0, dW1, db1, dg1, de1, dW2, db2, dg2, de2,
        out + 24832, g2);
    final_kernel<<<96, 256, 0, stream>>>(g2, doW, dob, out);
}

// Round 18
// 293.836 us; speedup vs baseline: 3.7894x; 1.1216x over previous
//
#include <hip/hip_runtime.h>
#include <math.h>

#define NBLK 256   // encoder blocks: 8 waves (512 thr), 1 block/CU (LDS-limited)

typedef float    f32x4 __attribute__((ext_vector_type(4)));
typedef _Float16 f16x4 __attribute__((ext_vector_type(4)));
typedef _Float16 f16x2 __attribute__((ext_vector_type(2)));
typedef _Float16 f16x8 __attribute__((ext_vector_type(8)));

// classic MFMA spelling (pre-gfx950 builtins have no underscore before the type)
#define MFMA16(A,B,C) __builtin_amdgcn_mfma_f32_16x16x16f16((A),(B),(C),0,0,0)

// ---------- math helpers ----------
__device__ __forceinline__ float fast_rcp(float x) {
#if __has_builtin(__builtin_amdgcn_rcpf)
    return __builtin_amdgcn_rcpf(x);
#else
    return 1.0f / x;
#endif
}

// exact GELU: 0.5*x*(1+erf(x/sqrt(2))), erf via Abramowitz-Stegun 7.1.26 (|err|<1.5e-7)
__device__ __forceinline__ float gelu_exact(float x) {
    float u  = x * 0.70710678118654752440f;
    float au = fabsf(u);
    float t  = fast_rcp(fmaf(0.3275911f, au, 1.0f));
    float p  = t * fmaf(t, fmaf(t, fmaf(t, fmaf(t, 1.061405429f, -1.453152027f),
                       1.421413741f), -0.284496736f), 0.254829592f);
    float e  = __expf(-(au * au));
    float er = fmaf(-p, e, 1.0f);
    er = copysignf(er, u);
    return 0.5f * x * (1.0f + er);
}

__device__ __forceinline__ f16x2 pk_from(float a, float b) {
#if __has_builtin(__builtin_amdgcn_cvt_pkrtz)
    auto r = __builtin_amdgcn_cvt_pkrtz(a, b);   // __fp16 ext_vector(2): same bits
    f16x2 out;
    __builtin_memcpy(&out, &r, sizeof(out));
    return out;
#else
    return (f16x2){(_Float16)a, (_Float16)b};
#endif
}

// packed (min|max) tracker: slot0 = running min, slot1 = running max
__device__ __forceinline__ f16x2 mm_update(f16x2 acc, f16x2 cand) {
    f16x2 r;
    r[0] = (cand[0] < acc[0]) ? cand[0] : acc[0];
    r[1] = (cand[1] > acc[1]) ? cand[1] : acc[1];
    return r;
}

// ---------- fused encoder: zero-barrier MFMA (r11/r14 structure) + GELU-maxpool commute ----------
// r16 diagnosis: issue-bound at 2 waves/SIMD; L2's per-point GELU chain = ~47% of
// the instruction stream. KEY: gelu is VALLEY-SHAPED (one minimum at x~-0.7518), so
// over any finite set max(gelu(v)) = max(gelu(min v), gelu(max v)). L2 gelu feeds
// ONLY the max-pool -> track per-channel (min,max) of normalized pre-gelu values
// (packed f16x2, register-neutral vs old f32 run[16]) and apply 2 gelus per channel
// per WAVE at the epilogue. Per-subset gelu-max is associative, so downstream fmax
// merges (cross-l4, cross-wave, cross-block) remain exact.
__global__ void __launch_bounds__(512, 1)
enc_kernel(const float* __restrict__ pts, int N,
           const float* __restrict__ W0, const float* __restrict__ B0,
           const float* __restrict__ G0, const float* __restrict__ E0,
           const float* __restrict__ W1, const float* __restrict__ B1,
           const float* __restrict__ G1, const float* __restrict__ E1,
           const float* __restrict__ W2, const float* __restrict__ B2,
           const float* __restrict__ G2, const float* __restrict__ E2,
           float* __restrict__ part)
{
    __shared__ __align__(16) _Float16 w1q[8*2*64*8];     // 16 KB  [nt][ks2][lane][8]
    __shared__ __align__(16) _Float16 w2q[16*4*64*8];    // 64 KB  [nt][ks2][lane][8]
    __shared__ __align__(16) _Float16 actL1[8][16*132];  // 33 KB  L1 acts (stride 132)
    __shared__ __align__(16) _Float16 scr[8][16*132];    // 33 KB  L0 acts / L2 packed park
    __shared__ __align__(16) float v1s[384];             // B1|G1|E1
    __shared__ __align__(16) float v2s[768];             // B2|G2|E2

    const int tid  = threadIdx.x;
    const int lane = tid & 63;
    const int wid  = tid >> 6;     // 0..7
    const int l15  = lane & 15;
    const int l4   = lane >> 4;    // 0..3

    // ---- one-time: pack W1/W2 into paired-ks B-fragment order ----
    #pragma unroll
    for (int e = 0; e < 2; ++e) {   // w1q: 8nt x 2ks2 x 64 = 1024 entries
        int idx = tid + e*512;
        int l = idx & 63, ks2 = (idx >> 6) & 1, nt = idx >> 7;
        f16x8 v;
        #pragma unroll
        for (int jj = 0; jj < 8; ++jj) {
            int ks = ks2*2 + (jj >> 2), j = jj & 3;
            int k  = ks*16 + ((l >> 4) << 2) + j;
            v[jj] = (_Float16)W1[k*128 + nt*16 + (l & 15)];
        }
        *(f16x8*)&w1q[idx*8] = v;
    }
    #pragma unroll
    for (int e = 0; e < 8; ++e) {   // w2q: 16nt x 4ks2 x 64 = 4096 entries
        int idx = tid + e*512;
        int l = idx & 63, ks2 = (idx >> 6) & 3, nt = idx >> 8;
        f16x8 v;
        #pragma unroll
        for (int jj = 0; jj < 8; ++jj) {
            int ks = ks2*2 + (jj >> 2), j = jj & 3;
            int k  = ks*16 + ((l >> 4) << 2) + j;
            v[jj] = (_Float16)W2[k*256 + nt*16 + (l & 15)];
        }
        *(f16x8*)&w2q[idx*8] = v;
    }
    if (tid < 128) { v1s[tid] = B1[tid]; v1s[128 + tid] = G1[tid]; v1s[256 + tid] = E1[tid]; }
    if (tid >= 256) {
        int c = tid - 256;
        v2s[c] = B2[c]; v2s[256 + c] = G2[c]; v2s[512 + c] = E2[c];
    }

    // ---- tile-invariant regs: W0 B-fragments + L0 bias/gain (ch = nt*16+l15) ----
    f16x4 w0f[4];
    float b0v[4], g0v[4], e0v[4];
    #pragma unroll
    for (int nt = 0; nt < 4; ++nt) {
        int ch = nt*16 + l15;
        #pragma unroll
        for (int j = 0; j < 4; ++j) {
            int k = l4*4 + j;
            w0f[nt][j] = (_Float16)((k < 3) ? W0[k*64 + ch] : 0.0f);
        }
        b0v[nt] = B0[ch]; g0v[nt] = G0[ch]; e0v[nt] = E0[ch];
    }
    __syncthreads();

    f16x2 run[16];
    #pragma unroll
    for (int nt = 0; nt < 16; ++nt)
        run[nt] = (f16x2){(_Float16)INFINITY, (_Float16)(-INFINITY)};

    const int tiles = (N + 127) >> 7;
    for (int t = blockIdx.x; t < tiles; t += NBLK) {
        const int pbase = t*128 + wid*16;          // this wave's 16 points
        // ---- L0: A built from coords (row = l15 = point, k = l4*4+j) ----
        f16x4 A0 = {(_Float16)0, (_Float16)0, (_Float16)0, (_Float16)0};
        {
            int p = pbase + l15;
            if (l4 == 0 && p < N) {
                A0[0] = (_Float16)pts[p*3];
                A0[1] = (_Float16)pts[p*3+1];
                A0[2] = (_Float16)pts[p*3+2];
            }
        }
        f32x4 acc0[4];
        #pragma unroll
        for (int nt = 0; nt < 4; ++nt) {
            acc0[nt] = (f32x4){b0v[nt], b0v[nt], b0v[nt], b0v[nt]};
            acc0[nt] = MFMA16(A0, w0f[nt], acc0[nt]);
        }
        {   // LN(64) in-wave + GELU -> scr rows (stride 68)
            f32x4 s4 = (acc0[0] + acc0[1]) + (acc0[2] + acc0[3]);
            f32x4 q4 = (acc0[0]*acc0[0] + acc0[1]*acc0[1]) + (acc0[2]*acc0[2] + acc0[3]*acc0[3]);
            #pragma unroll
            for (int m = 1; m < 16; m <<= 1)
                #pragma unroll
                for (int i = 0; i < 4; ++i) {
                    s4[i] += __shfl_xor(s4[i], m, 64);
                    q4[i] += __shfl_xor(q4[i], m, 64);
                }
            f32x4 mu, rs;
            #pragma unroll
            for (int i = 0; i < 4; ++i) {
                float m_ = s4[i] * (1.0f/64.0f);
                float v_ = q4[i] * (1.0f/64.0f) - m_*m_;
                mu[i] = m_; rs[i] = rsqrtf(v_ + 1e-5f);
            }
            #pragma unroll
            for (int nt = 0; nt < 4; ++nt)
                #pragma unroll
                for (int r = 0; r < 4; ++r) {
                    float v = fmaf((acc0[nt][r]-mu[r])*rs[r], g0v[nt], e0v[nt]);
                    scr[wid][(l4*4+r)*68 + nt*16 + l15] = (_Float16)gelu_exact(v);
                }
        }

        // ---- L1: 64 -> 128 (8 nt x 4 ks) ----
        f32x4 acc1[8];
        #pragma unroll
        for (int nt = 0; nt < 8; ++nt) {
            float b = v1s[nt*16 + l15];
            acc1[nt] = (f32x4){b, b, b, b};
        }
        #pragma unroll
        for (int ks2 = 0; ks2 < 2; ++ks2) {
            f16x4 Aa = *(const f16x4*)&scr[wid][l15*68 + (ks2*2+0)*16 + l4*4];
            f16x4 Ab = *(const f16x4*)&scr[wid][l15*68 + (ks2*2+1)*16 + l4*4];
            #pragma unroll
            for (int nt = 0; nt < 8; ++nt) {
                f16x8 bb = *(const f16x8*)&w1q[((nt*2 + ks2)*64 + lane)*8];
                f16x4 blo = __builtin_shufflevector(bb, bb, 0,1,2,3);
                f16x4 bhi = __builtin_shufflevector(bb, bb, 4,5,6,7);
                acc1[nt] = MFMA16(Aa, blo, acc1[nt]);
                acc1[nt] = MFMA16(Ab, bhi, acc1[nt]);
            }
        }
        {   // LN(128) in-wave + GELU -> actL1 rows (stride 132)
            f32x4 s4 = ((acc1[0]+acc1[1])+(acc1[2]+acc1[3])) + ((acc1[4]+acc1[5])+(acc1[6]+acc1[7]));
            f32x4 q4 = ((acc1[0]*acc1[0]+acc1[1]*acc1[1])+(acc1[2]*acc1[2]+acc1[3]*acc1[3]))
                     + ((acc1[4]*acc1[4]+acc1[5]*acc1[5])+(acc1[6]*acc1[6]+acc1[7]*acc1[7]));
            #pragma unroll
            for (int m = 1; m < 16; m <<= 1)
                #pragma unroll
                for (int i = 0; i < 4; ++i) {
                    s4[i] += __shfl_xor(s4[i], m, 64);
                    q4[i] += __shfl_xor(q4[i], m, 64);
                }
            f32x4 mu, rs;
            #pragma unroll
            for (int i = 0; i < 4; ++i) {
                float m_ = s4[i] * (1.0f/128.0f);
                float v_ = q4[i] * (1.0f/128.0f) - m_*m_;
                mu[i] = m_; rs[i] = rsqrtf(v_ + 1e-5f);
            }
            #pragma unroll
            for (int nt = 0; nt < 8; ++nt) {
                float g = v1s[128 + nt*16 + l15], e = v1s[256 + nt*16 + l15];
                #pragma unroll
                for (int r = 0; r < 4; ++r) {
                    float v = fmaf((acc1[nt][r]-mu[r])*rs[r], g, e);
                    actL1[wid][(l4*4+r)*132 + nt*16 + l15] = (_Float16)gelu_exact(v);
                }
            }
        }

        // ---- L2: 128 -> 256, two passes of 8 nt; NO per-point gelu (min/max commute) ----
        f32x4 sT = {0,0,0,0}, qT = {0,0,0,0};
        f32x4 acc2[8];
        // pass A: nt 0..7 -> packed f16 park (b64, same-lane round trip) + f32 stats
        #pragma unroll
        for (int nt = 0; nt < 8; ++nt) {
            float b = v2s[nt*16 + l15];
            acc2[nt] = (f32x4){b, b, b, b};
        }
        #pragma unroll
        for (int ks2 = 0; ks2 < 4; ++ks2) {
            f16x4 Aa = *(const f16x4*)&actL1[wid][l15*132 + (ks2*2+0)*16 + l4*4];
            f16x4 Ab = *(const f16x4*)&actL1[wid][l15*132 + (ks2*2+1)*16 + l4*4];
            #pragma unroll
            for (int nt = 0; nt < 8; ++nt) {
                f16x8 bb = *(const f16x8*)&w2q[((nt*4 + ks2)*64 + lane)*8];
                f16x4 blo = __builtin_shufflevector(bb, bb, 0,1,2,3);
                f16x4 bhi = __builtin_shufflevector(bb, bb, 4,5,6,7);
                acc2[nt] = MFMA16(Aa, blo, acc2[nt]);
                acc2[nt] = MFMA16(Ab, bhi, acc2[nt]);
            }
        }
        #pragma unroll
        for (int nt = 0; nt < 8; ++nt) {
            sT += acc2[nt];
            qT += acc2[nt]*acc2[nt];
            f16x2 lo = pk_from(acc2[nt][0], acc2[nt][1]);
            f16x2 hi = pk_from(acc2[nt][2], acc2[nt][3]);
            f16x4 pk = (f16x4){lo[0], lo[1], hi[0], hi[1]};
            *(f16x4*)&scr[wid][(nt*64 + lane)*4] = pk;   // b64 store
        }
        // pass B: nt 8..15 -> stays in regs
        #pragma unroll
        for (int nt = 0; nt < 8; ++nt) {
            float b = v2s[(nt+8)*16 + l15];
            acc2[nt] = (f32x4){b, b, b, b};
        }
        #pragma unroll
        for (int ks2 = 0; ks2 < 4; ++ks2) {
            f16x4 Aa = *(const f16x4*)&actL1[wid][l15*132 + (ks2*2+0)*16 + l4*4];
            f16x4 Ab = *(const f16x4*)&actL1[wid][l15*132 + (ks2*2+1)*16 + l4*4];
            #pragma unroll
            for (int nt = 0; nt < 8; ++nt) {
                f16x8 bb = *(const f16x8*)&w2q[(((nt+8)*4 + ks2)*64 + lane)*8];
                f16x4 blo = __builtin_shufflevector(bb, bb, 0,1,2,3);
                f16x4 bhi = __builtin_shufflevector(bb, bb, 4,5,6,7);
                acc2[nt] = MFMA16(Aa, blo, acc2[nt]);
                acc2[nt] = MFMA16(Ab, bhi, acc2[nt]);
            }
        }
        #pragma unroll
        for (int nt = 0; nt < 8; ++nt) {
            sT += acc2[nt];
            qT += acc2[nt]*acc2[nt];
        }
        {   // LN(256) reduce; normalized pre-gelu values -> packed min/max tracking
            #pragma unroll
            for (int m = 1; m < 16; m <<= 1)
                #pragma unroll
                for (int i = 0; i < 4; ++i) {
                    sT[i] += __shfl_xor(sT[i], m, 64);
                    qT[i] += __shfl_xor(qT[i], m, 64);
                }
            f32x4 mu, rs;
            bool pv[4];
            #pragma unroll
            for (int i = 0; i < 4; ++i) {
                float m_ = sT[i] * (1.0f/256.0f);
                float v_ = qT[i] * (1.0f/256.0f) - m_*m_;
                mu[i] = m_; rs[i] = rsqrtf(v_ + 1e-5f);
                pv[i] = (pbase + l4*4 + i) < N;
            }
            const bool tfull = (pbase + 16) <= N;   // wave-uniform fast path
            #pragma unroll
            for (int nt = 0; nt < 8; ++nt) {   // pass B channels (nt+8) from regs
                int ch = (nt+8)*16 + l15;
                float g = v2s[256 + ch], e = v2s[512 + ch];
                #pragma unroll
                for (int r = 0; r < 4; ++r) {
                    float v = fmaf((acc2[nt][r]-mu[r])*rs[r], g, e);
                    f16x2 cand = tfull ? pk_from(v, v)
                                       : pk_from(pv[r] ? v : INFINITY, pv[r] ? v : -INFINITY);
                    run[nt+8] = mm_update(run[nt+8], cand);
                }
            }
            #pragma unroll
            for (int nt = 0; nt < 8; ++nt) {   // pass A channels from packed park
                int ch = nt*16 + l15;
                float g = v2s[256 + ch], e = v2s[512 + ch];
                f16x4 pk = *(const f16x4*)&scr[wid][(nt*64 + lane)*4];
                #pragma unroll
                for (int r = 0; r < 4; ++r) {
                    float v = fmaf(((float)pk[r]-mu[r])*rs[r], g, e);
                    f16x2 cand = tfull ? pk_from(v, v)
                                       : pk_from(pv[r] ? v : INFINITY, pv[r] ? v : -INFINITY);
                    run[nt] = mm_update(run[nt], cand);
                }
            }
        }
    }

    // ---------- epilogue: merge min/max over l4, apply 2 gelus/channel, merge waves ----------
    __syncthreads();                       // all tile work done before overlaying
    float* pm = (float*)actL1;             // 8 KB region
    #pragma unroll
    for (int nt = 0; nt < 16; ++nt) {
        float mn = (float)run[nt][0];
        float mx = (float)run[nt][1];
        mn = fminf(mn, __shfl_xor(mn, 16, 64)); mn = fminf(mn, __shfl_xor(mn, 32, 64));
        mx = fmaxf(mx, __shfl_xor(mx, 16, 64)); mx = fmaxf(mx, __shfl_xor(mx, 32, 64));
        if (l4 == 0) {
            // valley-shape: max over this wave's points of gelu = max(gelu(mn), gelu(mx))
            float v = fmaxf(gelu_exact(mn), gelu_exact(mx));
            pm[wid*256 + nt*16 + l15] = v;
        }
    }
    __syncthreads();
    if (tid < 256) {
        float v = pm[tid];
        #pragma unroll
        for (int w = 1; w < 8; ++w) v = fmaxf(v, pm[w*256 + tid]);
        part[(size_t)blockIdx.x * 256 + tid] = v;
    }
}

// ---------- reduce partials -> pooled(256); z_e = pooled @ oW + ob ----------
__global__ void __launch_bounds__(256)
pool_ze_kernel(const float* __restrict__ part, const float* __restrict__ oW,
               const float* __restrict__ ob, float* __restrict__ out_ze,
               float* __restrict__ ws_ze)
{
    __shared__ float pooled[256];
    const int j = threadIdx.x;
    float m0 = -INFINITY, m1 = -INFINITY, m2 = -INFINITY, m3 = -INFINITY;
    for (int b = 0; b < NBLK; b += 4) {
        m0 = fmaxf(m0, part[(b+0)*256 + j]);
        m1 = fmaxf(m1, part[(b+1)*256 + j]);
        m2 = fmaxf(m2, part[(b+2)*256 + j]);
        m3 = fmaxf(m3, part[(b+3)*256 + j]);
    }
    pooled[j] = fmaxf(fmaxf(m0, m1), fmaxf(m2, m3));
    __syncthreads();
    float a0 = 0.f, a1 = 0.f;
    for (int k = 0; k < 256; k += 2) {
        a0 = fmaf(pooled[k],   oW[(k  )*256 + j], a0);
        a1 = fmaf(pooled[k+1], oW[(k+1)*256 + j], a1);
    }
    float z = (a0 + a1) + ob[j];
    out_ze[j] = z;
    ws_ze[j]  = z;
}

// ---------- distances over codebook + per-block argmin partials ----------
__global__ void __launch_bounds__(256)
quant_kernel(const float* __restrict__ cb, const float* __restrict__ ze,
             float* __restrict__ qpart)
{
    const int lane = threadIdx.x & 63;
    const int wid  = threadIdx.x >> 6;
    const int gw   = (int)blockIdx.x * 4 + wid;   // 256 waves total
    const float4* cb4 = (const float4*)cb;
    const float4* z4p = (const float4*)ze;
    const float4  z   = z4p[lane];

    float bv = INFINITY;
    int   bi = 0x7fffffff;
    for (int code = gw; code < 8192; code += 256) {
        float4 c = cb4[code*64 + lane];
        float d = c.x*c.x + c.y*c.y + c.z*c.z + c.w*c.w
                - 2.0f*(c.x*z.x + c.y*z.y + c.z*z.z + c.w*z.w);
        #pragma unroll
        for (int m = 1; m < 64; m <<= 1) d += __shfl_xor(d, m, 64);
        if (d < bv) { bv = d; bi = code; }   // per-wave codes ascending; strict < keeps first
    }
    __shared__ float sv[4];
    __shared__ int   si[4];
    if (lane == 0) { sv[wid] = bv; si[wid] = bi; }
    __syncthreads();
    if (threadIdx.x == 0) {
        float v = sv[0]; int i = si[0];
        for (int w = 1; w < 4; ++w)
            if (sv[w] < v || (sv[w] == v && si[w] < i)) { v = sv[w]; i = si[w]; }
        qpart[blockIdx.x*2]     = v;
        qpart[blockIdx.x*2 + 1] = __int_as_float(i);
    }
}

// ---------- decoder block body: x(KIN) @ W(KIN,512) + b -> LN(512) -> GELU ----------
template<int KIN>
__device__ __forceinline__ void dec_block_body(const float* xs, const float* __restrict__ W,
        const float* __restrict__ B, const float* __restrict__ G,
        const float* __restrict__ E, float* __restrict__ xout, float* red)
{
    const int j = threadIdx.x;  // 512 threads
    float a0=0,a1=0,a2=0,a3=0;
    for (int k = 0; k < KIN; k += 4) {
        a0 = fmaf(xs[k  ], W[(k  )*512 + j], a0);
        a1 = fmaf(xs[k+1], W[(k+1)*512 + j], a1);
        a2 = fmaf(xs[k+2], W[(k+2)*512 + j], a2);
        a3 = fmaf(xs[k+3], W[(k+3)*512 + j], a3);
    }
    float acc = ((a0+a1)+(a2+a3)) + B[j];
    float s = acc, q = acc*acc;
    #pragma unroll
    for (int m = 1; m < 64; m <<= 1) { s += __shfl_xor(s, m, 64); q += __shfl_xor(q, m, 64); }
    const int wid = j >> 6, lane = j & 63;
    if (lane == 0) { red[wid*2] = s; red[wid*2+1] = q; }
    __syncthreads();
    float ts = 0.f, tq = 0.f;
    #pragma unroll
    for (int w = 0; w < 8; ++w) { ts += red[w*2]; tq += red[w*2+1]; }
    float mu  = ts * (1.0f/512.0f);
    float var = tq * (1.0f/512.0f) - mu*mu;
    float v = fmaf((acc - mu) * rsqrtf(var + 1e-5f), G[j], E[j]);
    xout[j] = gelu_exact(v);
}

// ---------- fused tail: argmin + z_q + straight-through + decoder L0+L1+L2 ----------
__global__ void __launch_bounds__(512)
tail_kernel(const float* __restrict__ qpart, const float* __restrict__ cb,
            const float* __restrict__ ze,
            const float* __restrict__ W0d, const float* __restrict__ B0d,
            const float* __restrict__ G0d, const float* __restrict__ E0d,
            const float* __restrict__ W1d, const float* __restrict__ B1d,
            const float* __restrict__ G1d, const float* __restrict__ E1d,
            const float* __restrict__ W2d, const float* __restrict__ B2d,
            const float* __restrict__ G2d, const float* __restrict__ E2d,
            float* __restrict__ out_zq, float* __restrict__ g2_out)
{
    __shared__ float xa[512];
    __shared__ float xb[512];
    __shared__ float red[16];
    __shared__ int   sidx;
    const int j = threadIdx.x;

    // phase 0: final argmin
    if (j == 0) {
        float bv = INFINITY; int bi = 0x7fffffff;
        for (int b = 0; b < 64; ++b) {
            float v = qpart[b*2];
            int   i = __float_as_int(qpart[b*2 + 1]);
            if (v < bv || (v == bv && i < bi)) { bv = v; bi = i; }
        }
        sidx = bi;
    }
    __syncthreads();
    const int idx = sidx;

    // phase 1: z_q + straight-through -> xa[0:256); decoder L0 (256 -> 512) -> xb
    if (j < 256) {
        float zq = cb[(size_t)idx*256 + j];
        out_zq[j] = zq;
        float z = ze[j];
        xa[j] = z + (zq - z);   // straight-through forward, matching ref fp ops
    }
    __syncthreads();
    dec_block_body<256>(xa, W0d, B0d, G0d, E0d, xb, red);
    __syncthreads();

    // phase 2: decoder L1 (512 -> 512) -> xa
    dec_block_body<512>(xb, W1d, B1d, G1d, E1d, xa, red);
    __syncthreads();

    // phase 3: decoder L2 (512 -> 512) -> xb -> global
    dec_block_body<512>(xa, W2d, B2d, G2d, E2d, xb, red);
    __syncthreads();
    g2_out[j] = xb[j];
}

// ---------- final projection: recon = g(512) @ doW(512,24576) + dob ----------
__global__ void __launch_bounds__(256)
final_kernel(const float* __restrict__ g, const float* __restrict__ W,
             const float* __restrict__ B, float* __restrict__ out)
{
    __shared__ float gs[512];
    const int t = threadIdx.x;
    gs[t]       = g[t];
    gs[t + 256] = g[t + 256];
    __syncthreads();
    const int j = (int)blockIdx.x * 256 + t;
    float a0=0,a1=0,a2=0,a3=0;
    #pragma unroll 4
    for (int k = 0; k < 512; k += 4) {
        a0 = fmaf(gs[k  ], W[(size_t)(k  )*24576 + j], a0);
        a1 = fmaf(gs[k+1], W[(size_t)(k+1)*24576 + j], a1);
        a2 = fmaf(gs[k+2], W[(size_t)(k+2)*24576 + j], a2);
        a3 = fmaf(gs[k+3], W[(size_t)(k+3)*24576 + j], a3);
    }
    out[j] = ((a0+a1)+(a2+a3)) + B[j];
}

extern "C" void kernel_launch(void* const* d_in, const int* in_sizes, int n_in,
                              void* d_out, int out_size, void* d_ws, size_t ws_size,
                              hipStream_t stream)
{
    (void)n_in; (void)out_size; (void)ws_size;
    const float* pts = (const float*)d_in[0];
    const float* eW0 = (const float*)d_in[1];
    const float* eb0 = (const float*)d_in[2];
    const float* eg0 = (const float*)d_in[3];
    const float* ee0 = (const float*)d_in[4];
    const float* eW1 = (const float*)d_in[5];
    const float* eb1 = (const float*)d_in[6];
    const float* eg1 = (const float*)d_in[7];
    const float* ee1 = (const float*)d_in[8];
    const float* eW2 = (const float*)d_in[9];
    const float* eb2 = (const float*)d_in[10];
    const float* eg2 = (const float*)d_in[11];
    const float* ee2 = (const float*)d_in[12];
    const float* oW  = (const float*)d_in[13];
    const float* ob  = (const float*)d_in[14];
    const float* cb  = (const float*)d_in[15];
    const float* dW0 = (const float*)d_in[16];
    const float* db0 = (const float*)d_in[17];
    const float* dg0 = (const float*)d_in[18];
    const float* de0 = (const float*)d_in[19];
    const float* dW1 = (const float*)d_in[20];
    const float* db1 = (const float*)d_in[21];
    const float* dg1 = (const float*)d_in[22];
    const float* de1 = (const float*)d_in[23];
    const float* dW2 = (const float*)d_in[24];
    const float* db2 = (const float*)d_in[25];
    const float* dg2 = (const float*)d_in[26];
    const float* de2 = (const float*)d_in[27];
    const float* doW = (const float*)d_in[28];
    const float* dob = (const float*)d_in[29];

    float* out = (float*)d_out;
    float* ws  = (float*)d_ws;
    const int N = in_sizes[0] / 3;

    float* part = ws;                 // NBLK*256 = 65536 floats
    float* ze   = ws + 262144;        // 256
    float* qp   = ws + 262400;        // 128 (64 x {val, idx})
    float* g2   = ws + 263552;        // 512

    enc_kernel<<<NBLK, 512, 0, stream>>>(pts, N,
        eW0, eb0, eg0, ee0, eW1, eb1, eg1, ee1, eW2, eb2, eg2, ee2, part);
    pool_ze_kernel<<<1, 256, 0, stream>>>(part, oW, ob, out + 24576, ze);
    quant_kernel<<<64, 256, 0, stream>>>(cb, ze, qp);
    tail_kernel<<<1, 512, 0, stream>>>(qp, cb, ze,
        dW0, db0, dg0, de0, dW1, db1, dg1, de1, dW2, db2, dg2, de2,
        out + 24832, g2);
    final_kernel<<<96, 256, 0, stream>>>(g2, doW, dob, out);
}

// Round 19
// 289.881 us; speedup vs baseline: 3.8411x; 1.0136x over previous
//
#include <hip/hip_runtime.h>
#include <math.h>

#define NBLK 256   // encoder blocks: 8 waves (512 thr), 1 block/CU (LDS-limited)

typedef float    f32x4 __attribute__((ext_vector_type(4)));
typedef _Float16 f16x4 __attribute__((ext_vector_type(4)));
typedef _Float16 f16x2 __attribute__((ext_vector_type(2)));
typedef _Float16 f16x8 __attribute__((ext_vector_type(8)));

// classic MFMA spelling (pre-gfx950 builtins have no underscore before the type)
#define MFMA16(A,B,C) __builtin_amdgcn_mfma_f32_16x16x16f16((A),(B),(C),0,0,0)

// ---------- math helpers ----------
__device__ __forceinline__ float fast_rcp(float x) {
#if __has_builtin(__builtin_amdgcn_rcpf)
    return __builtin_amdgcn_rcpf(x);
#else
    return 1.0f / x;
#endif
}

// exact GELU: 0.5*x*(1+erf(x/sqrt(2))), erf via Abramowitz-Stegun 7.1.26 (|err|<1.5e-7)
// used on cold paths (epilogue: 32 calls/wave total; decoder tail)
__device__ __forceinline__ float gelu_exact(float x) {
    float u  = x * 0.70710678118654752440f;
    float au = fabsf(u);
    float t  = fast_rcp(fmaf(0.3275911f, au, 1.0f));
    float p  = t * fmaf(t, fmaf(t, fmaf(t, fmaf(t, 1.061405429f, -1.453152027f),
                       1.421413741f), -0.284496736f), 0.254829592f);
    float e  = __expf(-(au * au));
    float er = fmaf(-p, e, 1.0f);
    er = copysignf(er, u);
    return 0.5f * x * (1.0f + er);
}

// fast GELU (tanh form) for the hot L0/L1 path: |err vs exact| ~3e-4 absolute,
// far under the 0.124 threshold (current margin 0.0156). ~11 instr vs ~16.
__device__ __forceinline__ float gelu_fast(float x) {
    float x2 = x * x;
    float t  = 0.79788456080286536f * x * fmaf(0.044715f, x2, 1.0f);
    float at = fabsf(t);
    float ep = __expf(-2.0f * at);                 // e^{-2|t|}
    float th = 1.0f - 2.0f * ep * fast_rcp(1.0f + ep);   // tanh(|t|)
    th = copysignf(th, t);
    return 0.5f * x * (1.0f + th);
}

__device__ __forceinline__ f16x2 pk_from(float a, float b) {
#if __has_builtin(__builtin_amdgcn_cvt_pkrtz)
    auto r = __builtin_amdgcn_cvt_pkrtz(a, b);   // __fp16 ext_vector(2): same bits
    f16x2 out;
    __builtin_memcpy(&out, &r, sizeof(out));
    return out;
#else
    return (f16x2){(_Float16)a, (_Float16)b};
#endif
}

// packed (min|max) tracker: slot0 = running min, slot1 = running max
__device__ __forceinline__ f16x2 mm_update(f16x2 acc, f16x2 cand) {
    f16x2 r;
    r[0] = (cand[0] < acc[0]) ? cand[0] : acc[0];
    r[1] = (cand[1] > acc[1]) ? cand[1] : acc[1];
    return r;
}

// ---------- fused encoder: zero-barrier MFMA + GELU-maxpool commute + fast-gelu hot path ----------
// r18: commute verified (264us, absmax 0.0156). This round: tanh-gelu on L0/L1
// (48 gelus/lane/tile, the largest remaining VALU chunk); exact erf kept in
// epilogue + decoder. Everything else identical to r18.
__global__ void __launch_bounds__(512, 1)
enc_kernel(const float* __restrict__ pts, int N,
           const float* __restrict__ W0, const float* __restrict__ B0,
           const float* __restrict__ G0, const float* __restrict__ E0,
           const float* __restrict__ W1, const float* __restrict__ B1,
           const float* __restrict__ G1, const float* __restrict__ E1,
           const float* __restrict__ W2, const float* __restrict__ B2,
           const float* __restrict__ G2, const float* __restrict__ E2,
           float* __restrict__ part)
{
    __shared__ __align__(16) _Float16 w1q[8*2*64*8];     // 16 KB  [nt][ks2][lane][8]
    __shared__ __align__(16) _Float16 w2q[16*4*64*8];    // 64 KB  [nt][ks2][lane][8]
    __shared__ __align__(16) _Float16 actL1[8][16*132];  // 33 KB  L1 acts (stride 132)
    __shared__ __align__(16) _Float16 scr[8][16*132];    // 33 KB  L0 acts / L2 packed park
    __shared__ __align__(16) float v1s[384];             // B1|G1|E1
    __shared__ __align__(16) float v2s[768];             // B2|G2|E2

    const int tid  = threadIdx.x;
    const int lane = tid & 63;
    const int wid  = tid >> 6;     // 0..7
    const int l15  = lane & 15;
    const int l4   = lane >> 4;    // 0..3

    // ---- one-time: pack W1/W2 into paired-ks B-fragment order ----
    #pragma unroll
    for (int e = 0; e < 2; ++e) {   // w1q: 8nt x 2ks2 x 64 = 1024 entries
        int idx = tid + e*512;
        int l = idx & 63, ks2 = (idx >> 6) & 1, nt = idx >> 7;
        f16x8 v;
        #pragma unroll
        for (int jj = 0; jj < 8; ++jj) {
            int ks = ks2*2 + (jj >> 2), j = jj & 3;
            int k  = ks*16 + ((l >> 4) << 2) + j;
            v[jj] = (_Float16)W1[k*128 + nt*16 + (l & 15)];
        }
        *(f16x8*)&w1q[idx*8] = v;
    }
    #pragma unroll
    for (int e = 0; e < 8; ++e) {   // w2q: 16nt x 4ks2 x 64 = 4096 entries
        int idx = tid + e*512;
        int l = idx & 63, ks2 = (idx >> 6) & 3, nt = idx >> 8;
        f16x8 v;
        #pragma unroll
        for (int jj = 0; jj < 8; ++jj) {
            int ks = ks2*2 + (jj >> 2), j = jj & 3;
            int k  = ks*16 + ((l >> 4) << 2) + j;
            v[jj] = (_Float16)W2[k*256 + nt*16 + (l & 15)];
        }
        *(f16x8*)&w2q[idx*8] = v;
    }
    if (tid < 128) { v1s[tid] = B1[tid]; v1s[128 + tid] = G1[tid]; v1s[256 + tid] = E1[tid]; }
    if (tid >= 256) {
        int c = tid - 256;
        v2s[c] = B2[c]; v2s[256 + c] = G2[c]; v2s[512 + c] = E2[c];
    }

    // ---- tile-invariant regs: W0 B-fragments + L0 bias/gain (ch = nt*16+l15) ----
    f16x4 w0f[4];
    float b0v[4], g0v[4], e0v[4];
    #pragma unroll
    for (int nt = 0; nt < 4; ++nt) {
        int ch = nt*16 + l15;
        #pragma unroll
        for (int j = 0; j < 4; ++j) {
            int k = l4*4 + j;
            w0f[nt][j] = (_Float16)((k < 3) ? W0[k*64 + ch] : 0.0f);
        }
        b0v[nt] = B0[ch]; g0v[nt] = G0[ch]; e0v[nt] = E0[ch];
    }
    __syncthreads();

    f16x2 run[16];
    #pragma unroll
    for (int nt = 0; nt < 16; ++nt)
        run[nt] = (f16x2){(_Float16)INFINITY, (_Float16)(-INFINITY)};

    const int tiles = (N + 127) >> 7;
    for (int t = blockIdx.x; t < tiles; t += NBLK) {
        const int pbase = t*128 + wid*16;          // this wave's 16 points
        // ---- L0: A built from coords (row = l15 = point, k = l4*4+j) ----
        f16x4 A0 = {(_Float16)0, (_Float16)0, (_Float16)0, (_Float16)0};
        {
            int p = pbase + l15;
            if (l4 == 0 && p < N) {
                A0[0] = (_Float16)pts[p*3];
                A0[1] = (_Float16)pts[p*3+1];
                A0[2] = (_Float16)pts[p*3+2];
            }
        }
        f32x4 acc0[4];
        #pragma unroll
        for (int nt = 0; nt < 4; ++nt) {
            acc0[nt] = (f32x4){b0v[nt], b0v[nt], b0v[nt], b0v[nt]};
            acc0[nt] = MFMA16(A0, w0f[nt], acc0[nt]);
        }
        {   // LN(64) in-wave + fast GELU -> scr rows (stride 68)
            f32x4 s4 = (acc0[0] + acc0[1]) + (acc0[2] + acc0[3]);
            f32x4 q4 = (acc0[0]*acc0[0] + acc0[1]*acc0[1]) + (acc0[2]*acc0[2] + acc0[3]*acc0[3]);
            #pragma unroll
            for (int m = 1; m < 16; m <<= 1)
                #pragma unroll
                for (int i = 0; i < 4; ++i) {
                    s4[i] += __shfl_xor(s4[i], m, 64);
                    q4[i] += __shfl_xor(q4[i], m, 64);
                }
            f32x4 mu, rs;
            #pragma unroll
            for (int i = 0; i < 4; ++i) {
                float m_ = s4[i] * (1.0f/64.0f);
                float v_ = q4[i] * (1.0f/64.0f) - m_*m_;
                mu[i] = m_; rs[i] = rsqrtf(v_ + 1e-5f);
            }
            #pragma unroll
            for (int nt = 0; nt < 4; ++nt)
                #pragma unroll
                for (int r = 0; r < 4; ++r) {
                    float v = fmaf((acc0[nt][r]-mu[r])*rs[r], g0v[nt], e0v[nt]);
                    scr[wid][(l4*4+r)*68 + nt*16 + l15] = (_Float16)gelu_fast(v);
                }
        }

        // ---- L1: 64 -> 128 (8 nt x 4 ks) ----
        f32x4 acc1[8];
        #pragma unroll
        for (int nt = 0; nt < 8; ++nt) {
            float b = v1s[nt*16 + l15];
            acc1[nt] = (f32x4){b, b, b, b};
        }
        #pragma unroll
        for (int ks2 = 0; ks2 < 2; ++ks2) {
            f16x4 Aa = *(const f16x4*)&scr[wid][l15*68 + (ks2*2+0)*16 + l4*4];
            f16x4 Ab = *(const f16x4*)&scr[wid][l15*68 + (ks2*2+1)*16 + l4*4];
            #pragma unroll
            for (int nt = 0; nt < 8; ++nt) {
                f16x8 bb = *(const f16x8*)&w1q[((nt*2 + ks2)*64 + lane)*8];
                f16x4 blo = __builtin_shufflevector(bb, bb, 0,1,2,3);
                f16x4 bhi = __builtin_shufflevector(bb, bb, 4,5,6,7);
                acc1[nt] = MFMA16(Aa, blo, acc1[nt]);
                acc1[nt] = MFMA16(Ab, bhi, acc1[nt]);
            }
        }
        {   // LN(128) in-wave + fast GELU -> actL1 rows (stride 132)
            f32x4 s4 = ((acc1[0]+acc1[1])+(acc1[2]+acc1[3])) + ((acc1[4]+acc1[5])+(acc1[6]+acc1[7]));
            f32x4 q4 = ((acc1[0]*acc1[0]+acc1[1]*acc1[1])+(acc1[2]*acc1[2]+acc1[3]*acc1[3]))
                     + ((acc1[4]*acc1[4]+acc1[5]*acc1[5])+(acc1[6]*acc1[6]+acc1[7]*acc1[7]));
            #pragma unroll
            for (int m = 1; m < 16; m <<= 1)
                #pragma unroll
                for (int i = 0; i < 4; ++i) {
                    s4[i] += __shfl_xor(s4[i], m, 64);
                    q4[i] += __shfl_xor(q4[i], m, 64);
                }
            f32x4 mu, rs;
            #pragma unroll
            for (int i = 0; i < 4; ++i) {
                float m_ = s4[i] * (1.0f/128.0f);
                float v_ = q4[i] * (1.0f/128.0f) - m_*m_;
                mu[i] = m_; rs[i] = rsqrtf(v_ + 1e-5f);
            }
            #pragma unroll
            for (int nt = 0; nt < 8; ++nt) {
                float g = v1s[128 + nt*16 + l15], e = v1s[256 + nt*16 + l15];
                #pragma unroll
                for (int r = 0; r < 4; ++r) {
                    float v = fmaf((acc1[nt][r]-mu[r])*rs[r], g, e);
                    actL1[wid][(l4*4+r)*132 + nt*16 + l15] = (_Float16)gelu_fast(v);
                }
            }
        }

        // ---- L2: 128 -> 256, two passes of 8 nt; NO per-point gelu (min/max commute) ----
        f32x4 sT = {0,0,0,0}, qT = {0,0,0,0};
        f32x4 acc2[8];
        // pass A: nt 0..7 -> packed f16 park (b64, same-lane round trip) + f32 stats
        #pragma unroll
        for (int nt = 0; nt < 8; ++nt) {
            float b = v2s[nt*16 + l15];
            acc2[nt] = (f32x4){b, b, b, b};
        }
        #pragma unroll
        for (int ks2 = 0; ks2 < 4; ++ks2) {
            f16x4 Aa = *(const f16x4*)&actL1[wid][l15*132 + (ks2*2+0)*16 + l4*4];
            f16x4 Ab = *(const f16x4*)&actL1[wid][l15*132 + (ks2*2+1)*16 + l4*4];
            #pragma unroll
            for (int nt = 0; nt < 8; ++nt) {
                f16x8 bb = *(const f16x8*)&w2q[((nt*4 + ks2)*64 + lane)*8];
                f16x4 blo = __builtin_shufflevector(bb, bb, 0,1,2,3);
                f16x4 bhi = __builtin_shufflevector(bb, bb, 4,5,6,7);
                acc2[nt] = MFMA16(Aa, blo, acc2[nt]);
                acc2[nt] = MFMA16(Ab, bhi, acc2[nt]);
            }
        }
        #pragma unroll
        for (int nt = 0; nt < 8; ++nt) {
            sT += acc2[nt];
            qT += acc2[nt]*acc2[nt];
            f16x2 lo = pk_from(acc2[nt][0], acc2[nt][1]);
            f16x2 hi = pk_from(acc2[nt][2], acc2[nt][3]);
            f16x4 pk = (f16x4){lo[0], lo[1], hi[0], hi[1]};
            *(f16x4*)&scr[wid][(nt*64 + lane)*4] = pk;   // b64 store
        }
        // pass B: nt 8..15 -> stays in regs
        #pragma unroll
        for (int nt = 0; nt < 8; ++nt) {
            float b = v2s[(nt+8)*16 + l15];
            acc2[nt] = (f32x4){b, b, b, b};
        }
        #pragma unroll
        for (int ks2 = 0; ks2 < 4; ++ks2) {
            f16x4 Aa = *(const f16x4*)&actL1[wid][l15*132 + (ks2*2+0)*16 + l4*4];
            f16x4 Ab = *(const f16x4*)&actL1[wid][l15*132 + (ks2*2+1)*16 + l4*4];
            #pragma unroll
            for (int nt = 0; nt < 8; ++nt) {
                f16x8 bb = *(const f16x8*)&w2q[(((nt+8)*4 + ks2)*64 + lane)*8];
                f16x4 blo = __builtin_shufflevector(bb, bb, 0,1,2,3);
                f16x4 bhi = __builtin_shufflevector(bb, bb, 4,5,6,7);
                acc2[nt] = MFMA16(Aa, blo, acc2[nt]);
                acc2[nt] = MFMA16(Ab, bhi, acc2[nt]);
            }
        }
        #pragma unroll
        for (int nt = 0; nt < 8; ++nt) {
            sT += acc2[nt];
            qT += acc2[nt]*acc2[nt];
        }
        {   // LN(256) reduce; normalized pre-gelu values -> packed min/max tracking
            #pragma unroll
            for (int m = 1; m < 16; m <<= 1)
                #pragma unroll
                for (int i = 0; i < 4; ++i) {
                    sT[i] += __shfl_xor(sT[i], m, 64);
                    qT[i] += __shfl_xor(qT[i], m, 64);
                }
            f32x4 mu, rs;
            bool pv[4];
            #pragma unroll
            for (int i = 0; i < 4; ++i) {
                float m_ = sT[i] * (1.0f/256.0f);
                float v_ = qT[i] * (1.0f/256.0f) - m_*m_;
                mu[i] = m_; rs[i] = rsqrtf(v_ + 1e-5f);
                pv[i] = (pbase + l4*4 + i) < N;
            }
            const bool tfull = (pbase + 16) <= N;   // wave-uniform fast path
            #pragma unroll
            for (int nt = 0; nt < 8; ++nt) {   // pass B channels (nt+8) from regs
                int ch = (nt+8)*16 + l15;
                float g = v2s[256 + ch], e = v2s[512 + ch];
                #pragma unroll
                for (int r = 0; r < 4; ++r) {
                    float v = fmaf((acc2[nt][r]-mu[r])*rs[r], g, e);
                    f16x2 cand = tfull ? pk_from(v, v)
                                       : pk_from(pv[r] ? v : INFINITY, pv[r] ? v : -INFINITY);
                    run[nt+8] = mm_update(run[nt+8], cand);
                }
            }
            #pragma unroll
            for (int nt = 0; nt < 8; ++nt) {   // pass A channels from packed park
                int ch = nt*16 + l15;
                float g = v2s[256 + ch], e = v2s[512 + ch];
                f16x4 pk = *(const f16x4*)&scr[wid][(nt*64 + lane)*4];
                #pragma unroll
                for (int r = 0; r < 4; ++r) {
                    float v = fmaf(((float)pk[r]-mu[r])*rs[r], g, e);
                    f16x2 cand = tfull ? pk_from(v, v)
                                       : pk_from(pv[r] ? v : INFINITY, pv[r] ? v : -INFINITY);
                    run[nt] = mm_update(run[nt], cand);
                }
            }
        }
    }

    // ---------- epilogue: merge min/max over l4, apply 2 exact gelus/channel, merge waves ----------
    __syncthreads();                       // all tile work done before overlaying
    float* pm = (float*)actL1;             // 8 KB region
    #pragma unroll
    for (int nt = 0; nt < 16; ++nt) {
        float mn = (float)run[nt][0];
        float mx = (float)run[nt][1];
        mn = fminf(mn, __shfl_xor(mn, 16, 64)); mn = fminf(mn, __shfl_xor(mn, 32, 64));
        mx = fmaxf(mx, __shfl_xor(mx, 16, 64)); mx = fmaxf(mx, __shfl_xor(mx, 32, 64));
        if (l4 == 0) {
            // valley-shape: max over this wave's points of gelu = max(gelu(mn), gelu(mx))
            float v = fmaxf(gelu_exact(mn), gelu_exact(mx));
            pm[wid*256 + nt*16 + l15] = v;
        }
    }
    __syncthreads();
    if (tid < 256) {
        float v = pm[tid];
        #pragma unroll
        for (int w = 1; w < 8; ++w) v = fmaxf(v, pm[w*256 + tid]);
        part[(size_t)blockIdx.x * 256 + tid] = v;
    }
}

// ---------- reduce partials -> pooled(256); z_e = pooled @ oW + ob ----------
__global__ void __launch_bounds__(256)
pool_ze_kernel(const float* __restrict__ part, const float* __restrict__ oW,
               const float* __restrict__ ob, float* __restrict__ out_ze,
               float* __restrict__ ws_ze)
{
    __shared__ float pooled[256];
    const int j = threadIdx.x;
    float m0 = -INFINITY, m1 = -INFINITY, m2 = -INFINITY, m3 = -INFINITY;
    for (int b = 0; b < NBLK; b += 4) {
        m0 = fmaxf(m0, part[(b+0)*256 + j]);
        m1 = fmaxf(m1, part[(b+1)*256 + j]);
        m2 = fmaxf(m2, part[(b+2)*256 + j]);
        m3 = fmaxf(m3, part[(b+3)*256 + j]);
    }
    pooled[j] = fmaxf(fmaxf(m0, m1), fmaxf(m2, m3));
    __syncthreads();
    float a0 = 0.f, a1 = 0.f;
    for (int k = 0; k < 256; k += 2) {
        a0 = fmaf(pooled[k],   oW[(k  )*256 + j], a0);
        a1 = fmaf(pooled[k+1], oW[(k+1)*256 + j], a1);
    }
    float z = (a0 + a1) + ob[j];
    out_ze[j] = z;
    ws_ze[j]  = z;
}

// ---------- distances over codebook + per-block argmin partials ----------
__global__ void __launch_bounds__(256)
quant_kernel(const float* __restrict__ cb, const float* __restrict__ ze,
             float* __restrict__ qpart)
{
    const int lane = threadIdx.x & 63;
    const int wid  = threadIdx.x >> 6;
    const int gw   = (int)blockIdx.x * 4 + wid;   // 256 waves total
    const float4* cb4 = (const float4*)cb;
    const float4* z4p = (const float4*)ze;
    const float4  z   = z4p[lane];

    float bv = INFINITY;
    int   bi = 0x7fffffff;
    for (int code = gw; code < 8192; code += 256) {
        float4 c = cb4[code*64 + lane];
        float d = c.x*c.x + c.y*c.y + c.z*c.z + c.w*c.w
                - 2.0f*(c.x*z.x + c.y*z.y + c.z*z.z + c.w*z.w);
        #pragma unroll
        for (int m = 1; m < 64; m <<= 1) d += __shfl_xor(d, m, 64);
        if (d < bv) { bv = d; bi = code; }   // per-wave codes ascending; strict < keeps first
    }
    __shared__ float sv[4];
    __shared__ int   si[4];
    if (lane == 0) { sv[wid] = bv; si[wid] = bi; }
    __syncthreads();
    if (threadIdx.x == 0) {
        float v = sv[0]; int i = si[0];
        for (int w = 1; w < 4; ++w)
            if (sv[w] < v || (sv[w] == v && si[w] < i)) { v = sv[w]; i = si[w]; }
        qpart[blockIdx.x*2]     = v;
        qpart[blockIdx.x*2 + 1] = __int_as_float(i);
    }
}

// ---------- decoder block body: x(KIN) @ W(KIN,512) + b -> LN(512) -> GELU ----------
template<int KIN>
__device__ __forceinline__ void dec_block_body(const float* xs, const float* __restrict__ W,
        const float* __restrict__ B, const float* __restrict__ G,
        const float* __restrict__ E, float* __restrict__ xout, float* red)
{
    const int j = threadIdx.x;  // 512 threads
    float a0=0,a1=0,a2=0,a3=0;
    for (int k = 0; k < KIN; k += 4) {
        a0 = fmaf(xs[k  ], W[(k  )*512 + j], a0);
        a1 = fmaf(xs[k+1], W[(k+1)*512 + j], a1);
        a2 = fmaf(xs[k+2], W[(k+2)*512 + j], a2);
        a3 = fmaf(xs[k+3], W[(k+3)*512 + j], a3);
    }
    float acc = ((a0+a1)+(a2+a3)) + B[j];
    float s = acc, q = acc*acc;
    #pragma unroll
    for (int m = 1; m < 64; m <<= 1) { s += __shfl_xor(s, m, 64); q += __shfl_xor(q, m, 64); }
    const int wid = j >> 6, lane = j & 63;
    if (lane == 0) { red[wid*2] = s; red[wid*2+1] = q; }
    __syncthreads();
    float ts = 0.f, tq = 0.f;
    #pragma unroll
    for (int w = 0; w < 8; ++w) { ts += red[w*2]; tq += red[w*2+1]; }
    float mu  = ts * (1.0f/512.0f);
    float var = tq * (1.0f/512.0f) - mu*mu;
    float v = fmaf((acc - mu) * rsqrtf(var + 1e-5f), G[j], E[j]);
    xout[j] = gelu_exact(v);
}

// ---------- fused tail: argmin + z_q + straight-through + decoder L0+L1+L2 ----------
__global__ void __launch_bounds__(512)
tail_kernel(const float* __restrict__ qpart, const float* __restrict__ cb,
            const float* __restrict__ ze,
            const float* __restrict__ W0d, const float* __restrict__ B0d,
            const float* __restrict__ G0d, const float* __restrict__ E0d,
            const float* __restrict__ W1d, const float* __restrict__ B1d,
            const float* __restrict__ G1d, const float* __restrict__ E1d,
            const float* __restrict__ W2d, const float* __restrict__ B2d,
            const float* __restrict__ G2d, const float* __restrict__ E2d,
            float* __restrict__ out_zq, float* __restrict__ g2_out)
{
    __shared__ float xa[512];
    __shared__ float xb[512];
    __shared__ float red[16];
    __shared__ int   sidx;
    const int j = threadIdx.x;

    // phase 0: final argmin
    if (j == 0) {
        float bv = INFINITY; int bi = 0x7fffffff;
        for (int b = 0; b < 64; ++b) {
            float v = qpart[b*2];
            int   i = __float_as_int(qpart[b*2 + 1]);
            if (v < bv || (v == bv && i < bi)) { bv = v; bi = i; }
        }
        sidx = bi;
    }
    __syncthreads();
    const int idx = sidx;

    // phase 1: z_q + straight-through -> xa[0:256); decoder L0 (256 -> 512) -> xb
    if (j < 256) {
        float zq = cb[(size_t)idx*256 + j];
        out_zq[j] = zq;
        float z = ze[j];
        xa[j] = z + (zq - z);   // straight-through forward, matching ref fp ops
    }
    __syncthreads();
    dec_block_body<256>(xa, W0d, B0d, G0d, E0d, xb, red);
    __syncthreads();

    // phase 2: decoder L1 (512 -> 512) -> xa
    dec_block_body<512>(xb, W1d, B1d, G1d, E1d, xa, red);
    __syncthreads();

    // phase 3: decoder L2 (512 -> 512) -> xb -> global
    dec_block_body<512>(xa, W2d, B2d, G2d, E2d, xb, red);
    __syncthreads();
    g2_out[j] = xb[j];
}

// ---------- final projection: recon = g(512) @ doW(512,24576) + dob ----------
__global__ void __launch_bounds__(256)
final_kernel(const float* __restrict__ g, const float* __restrict__ W,
             const float* __restrict__ B, float* __restrict__ out)
{
    __shared__ float gs[512];
    const int t = threadIdx.x;
    gs[t]       = g[t];
    gs[t + 256] = g[t + 256];
    __syncthreads();
    const int j = (int)blockIdx.x * 256 + t;
    float a0=0,a1=0,a2=0,a3=0;
    #pragma unroll 4
    for (int k = 0; k < 512; k += 4) {
        a0 = fmaf(gs[k  ], W[(size_t)(k  )*24576 + j], a0);
        a1 = fmaf(gs[k+1], W[(size_t)(k+1)*24576 + j], a1);
        a2 = fmaf(gs[k+2], W[(size_t)(k+2)*24576 + j], a2);
        a3 = fmaf(gs[k+3], W[(size_t)(k+3)*24576 + j], a3);
    }
    out[j] = ((a0+a1)+(a2+a3)) + B[j];
}

extern "C" void kernel_launch(void* const* d_in, const int* in_sizes, int n_in,
                              void* d_out, int out_size, void* d_ws, size_t ws_size,
                              hipStream_t stream)
{
    (void)n_in; (void)out_size; (void)ws_size;
    const float* pts = (const float*)d_in[0];
    const float* eW0 = (const float*)d_in[1];
    const float* eb0 = (const float*)d_in[2];
    const float* eg0 = (const float*)d_in[3];
    const float* ee0 = (const float*)d_in[4];
    const float* eW1 = (const float*)d_in[5];
    const float* eb1 = (const float*)d_in[6];
    const float* eg1 = (const float*)d_in[7];
    const float* ee1 = (const float*)d_in[8];
    const float* eW2 = (const float*)d_in[9];
    const float* eb2 = (const float*)d_in[10];
    const float* eg2 = (const float*)d_in[11];
    const float* ee2 = (const float*)d_in[12];
    const float* oW  = (const float*)d_in[13];
    const float* ob  = (const float*)d_in[14];
    const float* cb  = (const float*)d_in[15];
    const float* dW0 = (const float*)d_in[16];
    const float* db0 = (const float*)d_in[17];
    const float* dg0 = (const float*)d_in[18];
    const float* de0 = (const float*)d_in[19];
    const float* dW1 = (const float*)d_in[20];
    const float* db1 = (const float*)d_in[21];
    const float* dg1 = (const float*)d_in[22];
    const float* de1 = (const float*)d_in[23];
    const float* dW2 = (const float*)d_in[24];
    const float* db2 = (const float*)d_in[25];
    const float* dg2 = (const float*)d_in[26];
    const float* de2 = (const float*)d_in[27];
    const float* doW = (const float*)d_in[28];
    const float* dob = (const float*)d_in[29];

    float* out = (float*)d_out;
    float* ws  = (float*)d_ws;
    const int N = in_sizes[0] / 3;

    float* part = ws;                 // NBLK*256 = 65536 floats
    float* ze   = ws + 262144;        // 256
    float* qp   = ws + 262400;        // 128 (64 x {val, idx})
    float* g2   = ws + 263552;        // 512

    enc_kernel<<<NBLK, 512, 0, stream>>>(pts, N,
        eW0, eb0, eg0, ee0, eW1, eb1, eg1, ee1, eW2, eb2, eg2, ee2, part);
    pool_ze_kernel<<<1, 256, 0, stream>>>(part, oW, ob, out + 24576, ze);
    quant_kernel<<<64, 256, 0, stream>>>(cb, ze, qp);
    tail_kernel<<<1, 512, 0, stream>>>(qp, cb, ze,
        dW0, db0, dg0, de0, dW1, db1, dg1, de1, dW2, db2, dg2, de2,
        out + 24832, g2);
    final_kernel<<<96, 256, 0, stream>>>(g2, doW, dob, out);
}